// Round 1
// baseline (1271.347 us; speedup 1.0000x reference)
//
#include <hip/hip_runtime.h>
#include <hip/hip_bf16.h>
#include <cstdint>
#include <cstddef>

// Problem constants
#define B_    2
#define S_    2048
#define HID_  2048
#define H_    32
#define HKV_  8
#define DH_   64
#define SCALE_ 0.125f

typedef __bf16 bf16;
typedef bf16  bf16x8 __attribute__((ext_vector_type(8)));
typedef float f32x4  __attribute__((ext_vector_type(4)));

__device__ __forceinline__ bf16x8 cvt8(float4 a, float4 b) {
    bf16x8 r;
    r[0] = (bf16)a.x; r[1] = (bf16)a.y; r[2] = (bf16)a.z; r[3] = (bf16)a.w;
    r[4] = (bf16)b.x; r[5] = (bf16)b.y; r[6] = (bf16)b.z; r[7] = (bf16)b.w;
    return r;
}

// ---------------------------------------------------------------------------
// QKV projection + fused RoPE.
// C = X (M=4096 x K=2048) * W^T (N x K), N = nh*64.
// Each block: 128 rows x 64 cols (one head). Each wave: 32 rows x 64 cols.
// Output layout: dst[b][head][s][d] as bf16 (attention-friendly).
// MFMA fragment layouts (HW-verified, 16x16x32_bf16):
//   A[m=lane&15][k=quad*8+j], B[k=quad*8+j][n=lane&15],
//   C/D: col=lane&15, row=quad*4+reg.
// RoPE: within a wave's 4 col-tiles (d in [0,64)), pair (d, d+-32) maps to
// tiles (0<->2, 1<->3), SAME lane & reg -> pure register epilogue.
// ---------------------------------------------------------------------------
__global__ __launch_bounds__(256) void proj_rope_kernel(
    const float* __restrict__ X, const float* __restrict__ W,
    const float* __restrict__ cs, const float* __restrict__ sn,
    bf16* __restrict__ dst, int nh, int do_rope)
{
    const int tid  = threadIdx.x;
    const int wave = tid >> 6;
    const int lane = tid & 63;
    const int quad = lane >> 4;
    const int l16  = lane & 15;
    const int m0   = blockIdx.x * 128;
    const int head = blockIdx.y;
    const int n0   = head * 64;
    const int mw   = m0 + wave * 32;

    f32x4 acc[2][4];
    #pragma unroll
    for (int rt = 0; rt < 2; ++rt)
        #pragma unroll
        for (int dt = 0; dt < 4; ++dt)
            acc[rt][dt] = (f32x4){0.f, 0.f, 0.f, 0.f};

    for (int k0 = 0; k0 < HID_; k0 += 32) {
        bf16x8 a[2];
        #pragma unroll
        for (int rt = 0; rt < 2; ++rt) {
            const float* xp = X + (size_t)(mw + rt * 16 + l16) * HID_ + k0 + quad * 8;
            a[rt] = cvt8(*(const float4*)xp, *(const float4*)(xp + 4));
        }
        #pragma unroll
        for (int dt = 0; dt < 4; ++dt) {
            const float* wp = W + (size_t)(n0 + dt * 16 + l16) * HID_ + k0 + quad * 8;
            bf16x8 bw = cvt8(*(const float4*)wp, *(const float4*)(wp + 4));
            acc[0][dt] = __builtin_amdgcn_mfma_f32_16x16x32_bf16(a[0], bw, acc[0][dt], 0, 0, 0);
            acc[1][dt] = __builtin_amdgcn_mfma_f32_16x16x32_bf16(a[1], bw, acc[1][dt], 0, 0, 0);
        }
    }

    // Epilogue
    #pragma unroll
    for (int rt = 0; rt < 2; ++rt) {
        #pragma unroll
        for (int r = 0; r < 4; ++r) {
            const int mrow = mw + rt * 16 + quad * 4 + r;
            const int bb = mrow >> 11;          // / S_
            const int ss = mrow & (S_ - 1);
            bf16* dp = dst + ((size_t)(bb * nh + head) * S_ + ss) * DH_;
            if (do_rope) {
                const float* cp = cs + ((size_t)bb * S_ + ss) * DH_;
                const float* sp = sn + ((size_t)bb * S_ + ss) * DH_;
                const float v0 = acc[rt][0][r], v1 = acc[rt][1][r];
                const float v2 = acc[rt][2][r], v3 = acc[rt][3][r];
                const int d = l16;
                dp[ 0 + d] = (bf16)(v0 * cp[ 0 + d] - v2 * sp[ 0 + d]);
                dp[16 + d] = (bf16)(v1 * cp[16 + d] - v3 * sp[16 + d]);
                dp[32 + d] = (bf16)(v2 * cp[32 + d] + v0 * sp[32 + d]);
                dp[48 + d] = (bf16)(v3 * cp[48 + d] + v1 * sp[48 + d]);
            } else {
                #pragma unroll
                for (int dt = 0; dt < 4; ++dt)
                    dp[dt * 16 + l16] = (bf16)acc[rt][dt][r];
            }
        }
    }
}

// ---------------------------------------------------------------------------
// Flash attention (causal, GQA). Block = 64 q-rows (4 waves x 16), K/V tiles
// of 64 in LDS (+72-stride pad vs bank conflicts). V staged transposed so the
// PV B-fragment is a contiguous ds_read_b128. P converts C-layout -> A-layout
// through a per-wave LDS round trip.
// ---------------------------------------------------------------------------
__global__ __launch_bounds__(256) void attn_kernel(
    const bf16* __restrict__ Q, const bf16* __restrict__ K,
    const bf16* __restrict__ V, bf16* __restrict__ O)
{
    __shared__ bf16 k_lds[64][72];
    __shared__ bf16 v_lds[64][72];      // transposed: v_lds[d][kpos]
    __shared__ bf16 p_lds[4][16][72];   // per-wave P buffer

    const int tid  = threadIdx.x;
    const int wave = tid >> 6;
    const int lane = tid & 63;
    const int quad = lane >> 4;
    const int l16  = lane & 15;
    const int qt = blockIdx.x;
    const int h  = blockIdx.y;
    const int b  = blockIdx.z;
    const int q0 = qt * 64;
    const int hkv = h >> 2;   // GROUPS = 4

    const bf16* Qb = Q + (size_t)(b * H_ + h) * S_ * DH_;
    const bf16* Kb = K + (size_t)(b * HKV_ + hkv) * S_ * DH_;
    const bf16* Vb = V + (size_t)(b * HKV_ + hkv) * S_ * DH_;

    const int qrow_base = q0 + wave * 16;

    // Q fragments (held for whole kernel)
    bf16x8 qf[2];
    qf[0] = *(const bf16x8*)(Qb + (size_t)(qrow_base + l16) * DH_ + 0  + quad * 8);
    qf[1] = *(const bf16x8*)(Qb + (size_t)(qrow_base + l16) * DH_ + 32 + quad * 8);

    f32x4 o_acc[4];
    #pragma unroll
    for (int dt = 0; dt < 4; ++dt) o_acc[dt] = (f32x4){0.f, 0.f, 0.f, 0.f};
    float m_i[4], l_i[4];
    #pragma unroll
    for (int r = 0; r < 4; ++r) { m_i[r] = -__builtin_inff(); l_i[r] = 0.f; }

    const int nkt = qt + 1;   // causal: only tiles with kpos <= q0+63
    for (int kt = 0; kt < nkt; ++kt) {
        __syncthreads();
        {
            const int r  = tid >> 2;
            const int c0 = (tid & 3) * 16;
            const bf16* kp = Kb + (size_t)(kt * 64 + r) * DH_ + c0;
            *(bf16x8*)(&k_lds[r][c0])     = *(const bf16x8*)kp;
            *(bf16x8*)(&k_lds[r][c0 + 8]) = *(const bf16x8*)(kp + 8);
            const bf16* vp = Vb + (size_t)(kt * 64 + r) * DH_ + c0;
            bf16x8 va = *(const bf16x8*)vp;
            bf16x8 vb = *(const bf16x8*)(vp + 8);
            #pragma unroll
            for (int i = 0; i < 8; ++i) {
                v_lds[c0 + i][r]     = va[i];
                v_lds[c0 + 8 + i][r] = vb[i];
            }
        }
        __syncthreads();

        // scores: 16 q-rows x 64 kpos (4 C-tiles)
        f32x4 sc[4];
        #pragma unroll
        for (int j = 0; j < 4; ++j) {
            f32x4 a = (f32x4){0.f, 0.f, 0.f, 0.f};
            #pragma unroll
            for (int ks = 0; ks < 2; ++ks) {
                bf16x8 kb = *(const bf16x8*)(&k_lds[j * 16 + l16][ks * 32 + quad * 8]);
                a = __builtin_amdgcn_mfma_f32_16x16x32_bf16(qf[ks], kb, a, 0, 0, 0);
            }
            sc[j] = a;
        }

        // scale + causal mask
        #pragma unroll
        for (int j = 0; j < 4; ++j) {
            const int kpos = kt * 64 + j * 16 + l16;
            #pragma unroll
            for (int r = 0; r < 4; ++r) {
                const int qr = qrow_base + quad * 4 + r;
                const float s = sc[j][r] * SCALE_;
                sc[j][r] = (kpos <= qr) ? s : -1e30f;
            }
        }

        // online softmax
        float mloc[4];
        #pragma unroll
        for (int r = 0; r < 4; ++r) {
            mloc[r] = fmaxf(fmaxf(sc[0][r], sc[1][r]), fmaxf(sc[2][r], sc[3][r]));
            #pragma unroll
            for (int off = 1; off < 16; off <<= 1)
                mloc[r] = fmaxf(mloc[r], __shfl_xor(mloc[r], off));
        }
        float alpha[4];
        #pragma unroll
        for (int r = 0; r < 4; ++r) {
            const float mn = fmaxf(m_i[r], mloc[r]);
            alpha[r] = __expf(m_i[r] - mn);
            m_i[r] = mn;
        }
        float rs[4] = {0.f, 0.f, 0.f, 0.f};
        #pragma unroll
        for (int j = 0; j < 4; ++j)
            #pragma unroll
            for (int r = 0; r < 4; ++r) {
                const float p = __expf(sc[j][r] - m_i[r]);
                sc[j][r] = p;
                rs[r] += p;
            }
        #pragma unroll
        for (int r = 0; r < 4; ++r) {
            #pragma unroll
            for (int off = 1; off < 16; off <<= 1)
                rs[r] += __shfl_xor(rs[r], off);
            l_i[r] = l_i[r] * alpha[r] + rs[r];
        }
        #pragma unroll
        for (int dt = 0; dt < 4; ++dt)
            #pragma unroll
            for (int r = 0; r < 4; ++r)
                o_acc[dt][r] *= alpha[r];

        // P: C-layout -> A-layout via per-wave LDS round trip (bf16)
        #pragma unroll
        for (int j = 0; j < 4; ++j)
            #pragma unroll
            for (int r = 0; r < 4; ++r)
                p_lds[wave][quad * 4 + r][j * 16 + l16] = (bf16)sc[j][r];

        bf16x8 pf[2];
        pf[0] = *(const bf16x8*)(&p_lds[wave][l16][0  + quad * 8]);
        pf[1] = *(const bf16x8*)(&p_lds[wave][l16][32 + quad * 8]);

        // PV: O[16 x 64] += P[16 x 64] * V[64 x 64]
        #pragma unroll
        for (int dt = 0; dt < 4; ++dt) {
            #pragma unroll
            for (int k2 = 0; k2 < 2; ++k2) {
                bf16x8 vb = *(const bf16x8*)(&v_lds[dt * 16 + l16][k2 * 32 + quad * 8]);
                o_acc[dt] = __builtin_amdgcn_mfma_f32_16x16x32_bf16(pf[k2], vb, o_acc[dt], 0, 0, 0);
            }
        }
    }

    // epilogue: normalize + store bf16 O[b][h][s][d]
    #pragma unroll
    for (int dt = 0; dt < 4; ++dt) {
        #pragma unroll
        for (int r = 0; r < 4; ++r) {
            const int qr = qrow_base + quad * 4 + r;
            const float val = o_acc[dt][r] / l_i[r];
            O[((size_t)(b * H_ + h) * S_ + qr) * DH_ + dt * 16 + l16] = (bf16)val;
        }
    }
}

// ---------------------------------------------------------------------------
// Output projection: Y (4096 x 2048) = O_flat (4096 x 2048, bf16, (b,h,s,d))
//                                      * Wo^T (2048 x 2048, fp32)
// k = h*64 + d; an 8-wide k-chunk never crosses a head (64 % 8 == 0).
// ---------------------------------------------------------------------------
__global__ __launch_bounds__(256) void outproj_kernel(
    const bf16* __restrict__ O, const float* __restrict__ Wo,
    float* __restrict__ Y)
{
    const int tid  = threadIdx.x;
    const int wave = tid >> 6;
    const int lane = tid & 63;
    const int quad = lane >> 4;
    const int l16  = lane & 15;
    const int m0 = blockIdx.x * 128;
    const int n0 = blockIdx.y * 64;
    const int mw = m0 + wave * 32;

    f32x4 acc[2][4];
    #pragma unroll
    for (int rt = 0; rt < 2; ++rt)
        #pragma unroll
        for (int dt = 0; dt < 4; ++dt)
            acc[rt][dt] = (f32x4){0.f, 0.f, 0.f, 0.f};

    for (int k0 = 0; k0 < HID_; k0 += 32) {
        const int k  = k0 + quad * 8;
        const int h  = k >> 6;
        const int dl = k & 63;
        bf16x8 a[2];
        #pragma unroll
        for (int rt = 0; rt < 2; ++rt) {
            const int mrow = mw + rt * 16 + l16;
            const int bb = mrow >> 11;
            const int ss = mrow & (S_ - 1);
            a[rt] = *(const bf16x8*)(O + ((size_t)(bb * H_ + h) * S_ + ss) * DH_ + dl);
        }
        #pragma unroll
        for (int dt = 0; dt < 4; ++dt) {
            const float* wp = Wo + (size_t)(n0 + dt * 16 + l16) * HID_ + k0 + quad * 8;
            bf16x8 bw = cvt8(*(const float4*)wp, *(const float4*)(wp + 4));
            acc[0][dt] = __builtin_amdgcn_mfma_f32_16x16x32_bf16(a[0], bw, acc[0][dt], 0, 0, 0);
            acc[1][dt] = __builtin_amdgcn_mfma_f32_16x16x32_bf16(a[1], bw, acc[1][dt], 0, 0, 0);
        }
    }

    #pragma unroll
    for (int rt = 0; rt < 2; ++rt)
        #pragma unroll
        for (int dt = 0; dt < 4; ++dt)
            #pragma unroll
            for (int r = 0; r < 4; ++r) {
                const int mrow = mw + rt * 16 + quad * 4 + r;
                Y[(size_t)mrow * HID_ + n0 + dt * 16 + l16] = acc[rt][dt][r];
            }
}

// ---------------------------------------------------------------------------
extern "C" void kernel_launch(void* const* d_in, const int* in_sizes, int n_in,
                              void* d_out, int out_size, void* d_ws, size_t ws_size,
                              hipStream_t stream)
{
    const float* X    = (const float*)d_in[0];   // (2, 2048, 2048)
    const float* cs   = (const float*)d_in[1];   // (2, 2048, 64)
    const float* sn   = (const float*)d_in[2];   // (2, 2048, 64)
    // d_in[3] = attention_mask (pure causal; implemented directly)
    const float* Wq   = (const float*)d_in[4];   // (2048, 2048)
    const float* Wk   = (const float*)d_in[5];   // (512, 2048)
    const float* Wv   = (const float*)d_in[6];   // (512, 2048)
    const float* Wo   = (const float*)d_in[7];   // (2048, 2048)
    float* Y          = (float*)d_out;           // (2, 2048, 2048)

    // workspace layout (bf16 elements)
    bf16* Qb = (bf16*)d_ws;                               // 2*32*2048*64 = 8388608
    bf16* Kb = Qb + (size_t)B_ * H_ * S_ * DH_;           // 2*8*2048*64  = 2097152
    bf16* Vb = Kb + (size_t)B_ * HKV_ * S_ * DH_;
    bf16* Ob = Vb + (size_t)B_ * HKV_ * S_ * DH_;         // 8388608
    // total = 20,971,520 elems * 2 B = 40 MiB

    dim3 blk(256);
    proj_rope_kernel<<<dim3(32, H_),   blk, 0, stream>>>(X, Wq, cs, sn, Qb, H_, 1);
    proj_rope_kernel<<<dim3(32, HKV_), blk, 0, stream>>>(X, Wk, cs, sn, Kb, HKV_, 1);
    proj_rope_kernel<<<dim3(32, HKV_), blk, 0, stream>>>(X, Wv, cs, sn, Vb, HKV_, 0);
    attn_kernel<<<dim3(S_ / 64, H_, B_), blk, 0, stream>>>(Qb, Kb, Vb, Ob);
    outproj_kernel<<<dim3(32, HID_ / 64), blk, 0, stream>>>(Ob, Wo, Y);
}

// Round 2
// 524.379 us; speedup vs baseline: 2.4245x; 2.4245x over previous
//
#include <hip/hip_runtime.h>
#include <hip/hip_bf16.h>
#include <cstdint>
#include <cstddef>

// Problem constants
#define B_    2
#define S_    2048
#define HID_  2048
#define H_    32
#define HKV_  8
#define DH_   64
#define SCALE_ 0.125f

typedef __bf16 bf16;
typedef bf16  bf16x8 __attribute__((ext_vector_type(8)));
typedef float f32x4  __attribute__((ext_vector_type(4)));

typedef __attribute__((address_space(3))) uint32_t  lds_u32_t;
typedef __attribute__((address_space(1))) const uint32_t glob_u32_t;

// async global->LDS, 16 B per lane. LDS dest is wave-uniform base + lane*16.
__device__ __forceinline__ void async16(const void* g, void* l) {
    __builtin_amdgcn_global_load_lds((glob_u32_t*)g, (lds_u32_t*)l, 16, 0, 0);
}

__device__ __forceinline__ bf16x8 cvt8(float4 a, float4 b) {
    bf16x8 r;
    r[0] = (bf16)a.x; r[1] = (bf16)a.y; r[2] = (bf16)a.z; r[3] = (bf16)a.w;
    r[4] = (bf16)b.x; r[5] = (bf16)b.y; r[6] = (bf16)b.z; r[7] = (bf16)b.w;
    return r;
}

// ---------------------------------------------------------------------------
// fp32 -> bf16 bulk convert, 8 elems/thread.
// ---------------------------------------------------------------------------
__global__ __launch_bounds__(256) void cvt_kernel(
    const float* __restrict__ in, bf16* __restrict__ out, int n8)
{
    const int i = blockIdx.x * 256 + threadIdx.x;
    if (i < n8) {
        float4 a = ((const float4*)in)[2 * i];
        float4 b = ((const float4*)in)[2 * i + 1];
        ((bf16x8*)out)[i] = cvt8(a, b);
    }
}

// ---------------------------------------------------------------------------
// m97-style GEMM core helpers. 128x128 tile, BK=64, 4 waves (2x2), each wave
// 64x64 (4x4 16x16 C-tiles). LDS tiles 128x64 bf16, linear row-major with
// XOR-(row&7) chunk swizzle: LDS 16B-chunk c of row r holds global columns
// ((c ^ (r&7))*8 .. +8). ds_read_b128 fragment reads then spread evenly over
// all 32 banks (8 dwords/bank = wave64-b128 minimum).
// Fragment layouts (HW-verified, mfma_f32_16x16x32_bf16):
//   A[m=lane&15][k=quad*8+j], B[k=quad*8+j][n=lane&15], C: col=l16,row=quad*4+r.
// ---------------------------------------------------------------------------

// Fused QKV projection: A = Xb (4096 x 2048), B rows n: [0,2048)=Wq,
// [2048,2560)=Wk, [2560,3072)=Wv. Epilogue: RoPE for Q/K, plain for V,
// writes (b, h, s, d) bf16.
__global__ __launch_bounds__(256) void gemm_qkv_kernel(
    const bf16* __restrict__ A,
    const bf16* __restrict__ Wqb, const bf16* __restrict__ Wkb,
    const bf16* __restrict__ Wvb,
    const float* __restrict__ cs, const float* __restrict__ sn,
    bf16* __restrict__ Qo, bf16* __restrict__ Ko, bf16* __restrict__ Vo)
{
    __shared__ bf16 a_lds[128 * 64];
    __shared__ bf16 b_lds[128 * 64];

    const int tid  = threadIdx.x;
    const int wave = tid >> 6;
    const int lane = tid & 63;
    const int quad = lane >> 4;
    const int l16  = lane & 15;
    const int wm   = wave >> 1;
    const int wn   = wave & 1;
    const int m0   = blockIdx.x * 128;
    const int n0   = blockIdx.y * 128;

    f32x4 acc[4][4];
    #pragma unroll
    for (int mt = 0; mt < 4; ++mt)
        #pragma unroll
        for (int nt = 0; nt < 4; ++nt)
            acc[mt][nt] = (f32x4){0.f, 0.f, 0.f, 0.f};

    // staging geometry (k0-invariant)
    int srow[4], sgcol[4];
    const bf16* browp[4];
    #pragma unroll
    for (int i = 0; i < 4; ++i) {
        const int e = tid * 8 + i * 2048;
        srow[i] = e >> 6;
        const int chunk = (e >> 3) & 7;
        sgcol[i] = (chunk ^ (srow[i] & 7)) << 3;
        const int n = n0 + srow[i];
        browp[i] = (n < 2048) ? (Wqb + (size_t)n * HID_)
                 : (n < 2560) ? (Wkb + (size_t)(n - 2048) * HID_)
                              : (Wvb + (size_t)(n - 2560) * HID_);
    }

    for (int k0 = 0; k0 < HID_; k0 += 64) {
        #pragma unroll
        for (int i = 0; i < 4; ++i) {
            async16(A + (size_t)(m0 + srow[i]) * HID_ + k0 + sgcol[i],
                    &a_lds[tid * 8 + i * 2048]);
            async16(browp[i] + k0 + sgcol[i],
                    &b_lds[tid * 8 + i * 2048]);
        }
        __syncthreads();
        #pragma unroll
        for (int ks = 0; ks < 2; ++ks) {
            bf16x8 af[4], bfr[4];
            #pragma unroll
            for (int mt = 0; mt < 4; ++mt) {
                const int row = wm * 64 + mt * 16 + l16;
                const int c = (ks * 4 + quad) ^ (row & 7);
                af[mt] = *(const bf16x8*)(&a_lds[row * 64 + c * 8]);
            }
            #pragma unroll
            for (int nt = 0; nt < 4; ++nt) {
                const int row = wn * 64 + nt * 16 + l16;
                const int c = (ks * 4 + quad) ^ (row & 7);
                bfr[nt] = *(const bf16x8*)(&b_lds[row * 64 + c * 8]);
            }
            #pragma unroll
            for (int mt = 0; mt < 4; ++mt)
                #pragma unroll
                for (int nt = 0; nt < 4; ++nt)
                    acc[mt][nt] = __builtin_amdgcn_mfma_f32_16x16x32_bf16(
                        af[mt], bfr[nt], acc[mt][nt], 0, 0, 0);
        }
        __syncthreads();
    }

    // Epilogue: wave's 64 cols = one head (d = nt*16 + l16), RoPE pairs 0<->2, 1<->3.
    const int nw = n0 + wn * 64;
    const int d  = l16;
    #pragma unroll
    for (int mt = 0; mt < 4; ++mt) {
        #pragma unroll
        for (int r = 0; r < 4; ++r) {
            const int m  = m0 + wm * 64 + mt * 16 + quad * 4 + r;
            const int bb = m >> 11;
            const int ss = m & (S_ - 1);
            const float v0 = acc[mt][0][r], v1 = acc[mt][1][r];
            const float v2 = acc[mt][2][r], v3 = acc[mt][3][r];
            if (nw < 2048) {
                const int h = nw >> 6;
                bf16* dp = Qo + ((size_t)(bb * H_ + h) * S_ + ss) * DH_;
                const float* cp = cs + ((size_t)bb * S_ + ss) * DH_;
                const float* sp = sn + ((size_t)bb * S_ + ss) * DH_;
                dp[ 0 + d] = (bf16)(v0 * cp[ 0 + d] - v2 * sp[ 0 + d]);
                dp[16 + d] = (bf16)(v1 * cp[16 + d] - v3 * sp[16 + d]);
                dp[32 + d] = (bf16)(v2 * cp[32 + d] + v0 * sp[32 + d]);
                dp[48 + d] = (bf16)(v3 * cp[48 + d] + v1 * sp[48 + d]);
            } else if (nw < 2560) {
                const int h = (nw - 2048) >> 6;
                bf16* dp = Ko + ((size_t)(bb * HKV_ + h) * S_ + ss) * DH_;
                const float* cp = cs + ((size_t)bb * S_ + ss) * DH_;
                const float* sp = sn + ((size_t)bb * S_ + ss) * DH_;
                dp[ 0 + d] = (bf16)(v0 * cp[ 0 + d] - v2 * sp[ 0 + d]);
                dp[16 + d] = (bf16)(v1 * cp[16 + d] - v3 * sp[16 + d]);
                dp[32 + d] = (bf16)(v2 * cp[32 + d] + v0 * sp[32 + d]);
                dp[48 + d] = (bf16)(v3 * cp[48 + d] + v1 * sp[48 + d]);
            } else {
                const int h = (nw - 2560) >> 6;
                bf16* dp = Vo + ((size_t)(bb * HKV_ + h) * S_ + ss) * DH_;
                dp[ 0 + d] = (bf16)v0;
                dp[16 + d] = (bf16)v1;
                dp[32 + d] = (bf16)v2;
                dp[48 + d] = (bf16)v3;
            }
        }
    }
}

// Output projection: Y (4096 x 2048 fp32) = Ob (4096 x 2048 bf16, (b,s,h*d))
// * Wob^T (2048 x 2048 bf16, N x K row-major).
__global__ __launch_bounds__(256) void gemm_out_kernel(
    const bf16* __restrict__ A, const bf16* __restrict__ Wb,
    float* __restrict__ Y)
{
    __shared__ bf16 a_lds[128 * 64];
    __shared__ bf16 b_lds[128 * 64];

    const int tid  = threadIdx.x;
    const int wave = tid >> 6;
    const int lane = tid & 63;
    const int quad = lane >> 4;
    const int l16  = lane & 15;
    const int wm   = wave >> 1;
    const int wn   = wave & 1;
    const int m0   = blockIdx.x * 128;
    const int n0   = blockIdx.y * 128;

    f32x4 acc[4][4];
    #pragma unroll
    for (int mt = 0; mt < 4; ++mt)
        #pragma unroll
        for (int nt = 0; nt < 4; ++nt)
            acc[mt][nt] = (f32x4){0.f, 0.f, 0.f, 0.f};

    int srow[4], sgcol[4];
    #pragma unroll
    for (int i = 0; i < 4; ++i) {
        const int e = tid * 8 + i * 2048;
        srow[i] = e >> 6;
        const int chunk = (e >> 3) & 7;
        sgcol[i] = (chunk ^ (srow[i] & 7)) << 3;
    }

    for (int k0 = 0; k0 < HID_; k0 += 64) {
        #pragma unroll
        for (int i = 0; i < 4; ++i) {
            async16(A + (size_t)(m0 + srow[i]) * HID_ + k0 + sgcol[i],
                    &a_lds[tid * 8 + i * 2048]);
            async16(Wb + (size_t)(n0 + srow[i]) * HID_ + k0 + sgcol[i],
                    &b_lds[tid * 8 + i * 2048]);
        }
        __syncthreads();
        #pragma unroll
        for (int ks = 0; ks < 2; ++ks) {
            bf16x8 af[4], bfr[4];
            #pragma unroll
            for (int mt = 0; mt < 4; ++mt) {
                const int row = wm * 64 + mt * 16 + l16;
                const int c = (ks * 4 + quad) ^ (row & 7);
                af[mt] = *(const bf16x8*)(&a_lds[row * 64 + c * 8]);
            }
            #pragma unroll
            for (int nt = 0; nt < 4; ++nt) {
                const int row = wn * 64 + nt * 16 + l16;
                const int c = (ks * 4 + quad) ^ (row & 7);
                bfr[nt] = *(const bf16x8*)(&b_lds[row * 64 + c * 8]);
            }
            #pragma unroll
            for (int mt = 0; mt < 4; ++mt)
                #pragma unroll
                for (int nt = 0; nt < 4; ++nt)
                    acc[mt][nt] = __builtin_amdgcn_mfma_f32_16x16x32_bf16(
                        af[mt], bfr[nt], acc[mt][nt], 0, 0, 0);
        }
        __syncthreads();
    }

    #pragma unroll
    for (int mt = 0; mt < 4; ++mt)
        #pragma unroll
        for (int nt = 0; nt < 4; ++nt)
            #pragma unroll
            for (int r = 0; r < 4; ++r) {
                const int m = m0 + wm * 64 + mt * 16 + quad * 4 + r;
                const int n = n0 + wn * 64 + nt * 16 + l16;
                Y[(size_t)m * HID_ + n] = acc[mt][nt][r];
            }
}

// ---------------------------------------------------------------------------
// Flash attention (causal, GQA). Unchanged from round 1 except O is written
// in flat (b, s, h*64+d) layout for the output projection.
// ---------------------------------------------------------------------------
__global__ __launch_bounds__(256) void attn_kernel(
    const bf16* __restrict__ Q, const bf16* __restrict__ K,
    const bf16* __restrict__ V, bf16* __restrict__ O)
{
    __shared__ bf16 k_lds[64][72];
    __shared__ bf16 v_lds[64][72];      // transposed: v_lds[d][kpos]
    __shared__ bf16 p_lds[4][16][72];   // per-wave P buffer

    const int tid  = threadIdx.x;
    const int wave = tid >> 6;
    const int lane = tid & 63;
    const int quad = lane >> 4;
    const int l16  = lane & 15;
    const int qt = blockIdx.x;
    const int h  = blockIdx.y;
    const int b  = blockIdx.z;
    const int q0 = qt * 64;
    const int hkv = h >> 2;   // GROUPS = 4

    const bf16* Qb = Q + (size_t)(b * H_ + h) * S_ * DH_;
    const bf16* Kb = K + (size_t)(b * HKV_ + hkv) * S_ * DH_;
    const bf16* Vb = V + (size_t)(b * HKV_ + hkv) * S_ * DH_;

    const int qrow_base = q0 + wave * 16;

    bf16x8 qf[2];
    qf[0] = *(const bf16x8*)(Qb + (size_t)(qrow_base + l16) * DH_ + 0  + quad * 8);
    qf[1] = *(const bf16x8*)(Qb + (size_t)(qrow_base + l16) * DH_ + 32 + quad * 8);

    f32x4 o_acc[4];
    #pragma unroll
    for (int dt = 0; dt < 4; ++dt) o_acc[dt] = (f32x4){0.f, 0.f, 0.f, 0.f};
    float m_i[4], l_i[4];
    #pragma unroll
    for (int r = 0; r < 4; ++r) { m_i[r] = -__builtin_inff(); l_i[r] = 0.f; }

    const int nkt = qt + 1;
    for (int kt = 0; kt < nkt; ++kt) {
        __syncthreads();
        {
            const int r  = tid >> 2;
            const int c0 = (tid & 3) * 16;
            const bf16* kp = Kb + (size_t)(kt * 64 + r) * DH_ + c0;
            *(bf16x8*)(&k_lds[r][c0])     = *(const bf16x8*)kp;
            *(bf16x8*)(&k_lds[r][c0 + 8]) = *(const bf16x8*)(kp + 8);
            const bf16* vp = Vb + (size_t)(kt * 64 + r) * DH_ + c0;
            bf16x8 va = *(const bf16x8*)vp;
            bf16x8 vb = *(const bf16x8*)(vp + 8);
            #pragma unroll
            for (int i = 0; i < 8; ++i) {
                v_lds[c0 + i][r]     = va[i];
                v_lds[c0 + 8 + i][r] = vb[i];
            }
        }
        __syncthreads();

        f32x4 sc[4];
        #pragma unroll
        for (int j = 0; j < 4; ++j) {
            f32x4 a = (f32x4){0.f, 0.f, 0.f, 0.f};
            #pragma unroll
            for (int ks = 0; ks < 2; ++ks) {
                bf16x8 kb = *(const bf16x8*)(&k_lds[j * 16 + l16][ks * 32 + quad * 8]);
                a = __builtin_amdgcn_mfma_f32_16x16x32_bf16(qf[ks], kb, a, 0, 0, 0);
            }
            sc[j] = a;
        }

        #pragma unroll
        for (int j = 0; j < 4; ++j) {
            const int kpos = kt * 64 + j * 16 + l16;
            #pragma unroll
            for (int r = 0; r < 4; ++r) {
                const int qr = qrow_base + quad * 4 + r;
                const float s = sc[j][r] * SCALE_;
                sc[j][r] = (kpos <= qr) ? s : -1e30f;
            }
        }

        float mloc[4];
        #pragma unroll
        for (int r = 0; r < 4; ++r) {
            mloc[r] = fmaxf(fmaxf(sc[0][r], sc[1][r]), fmaxf(sc[2][r], sc[3][r]));
            #pragma unroll
            for (int off = 1; off < 16; off <<= 1)
                mloc[r] = fmaxf(mloc[r], __shfl_xor(mloc[r], off));
        }
        float alpha[4];
        #pragma unroll
        for (int r = 0; r < 4; ++r) {
            const float mn = fmaxf(m_i[r], mloc[r]);
            alpha[r] = __expf(m_i[r] - mn);
            m_i[r] = mn;
        }
        float rs[4] = {0.f, 0.f, 0.f, 0.f};
        #pragma unroll
        for (int j = 0; j < 4; ++j)
            #pragma unroll
            for (int r = 0; r < 4; ++r) {
                const float p = __expf(sc[j][r] - m_i[r]);
                sc[j][r] = p;
                rs[r] += p;
            }
        #pragma unroll
        for (int r = 0; r < 4; ++r) {
            #pragma unroll
            for (int off = 1; off < 16; off <<= 1)
                rs[r] += __shfl_xor(rs[r], off);
            l_i[r] = l_i[r] * alpha[r] + rs[r];
        }
        #pragma unroll
        for (int dt = 0; dt < 4; ++dt)
            #pragma unroll
            for (int r = 0; r < 4; ++r)
                o_acc[dt][r] *= alpha[r];

        #pragma unroll
        for (int j = 0; j < 4; ++j)
            #pragma unroll
            for (int r = 0; r < 4; ++r)
                p_lds[wave][quad * 4 + r][j * 16 + l16] = (bf16)sc[j][r];

        bf16x8 pf[2];
        pf[0] = *(const bf16x8*)(&p_lds[wave][l16][0  + quad * 8]);
        pf[1] = *(const bf16x8*)(&p_lds[wave][l16][32 + quad * 8]);

        #pragma unroll
        for (int dt = 0; dt < 4; ++dt) {
            #pragma unroll
            for (int k2 = 0; k2 < 2; ++k2) {
                bf16x8 vb = *(const bf16x8*)(&v_lds[dt * 16 + l16][k2 * 32 + quad * 8]);
                o_acc[dt] = __builtin_amdgcn_mfma_f32_16x16x32_bf16(pf[k2], vb, o_acc[dt], 0, 0, 0);
            }
        }
    }

    // store O in flat (b, s, h*64+d)
    #pragma unroll
    for (int dt = 0; dt < 4; ++dt) {
        #pragma unroll
        for (int r = 0; r < 4; ++r) {
            const int qr = qrow_base + quad * 4 + r;
            const float val = o_acc[dt][r] / l_i[r];
            O[((size_t)(b * S_ + qr) * H_ + h) * DH_ + dt * 16 + l16] = (bf16)val;
        }
    }
}

// ---------------------------------------------------------------------------
extern "C" void kernel_launch(void* const* d_in, const int* in_sizes, int n_in,
                              void* d_out, int out_size, void* d_ws, size_t ws_size,
                              hipStream_t stream)
{
    const float* X    = (const float*)d_in[0];
    const float* cs   = (const float*)d_in[1];
    const float* sn   = (const float*)d_in[2];
    const float* Wq   = (const float*)d_in[4];
    const float* Wk   = (const float*)d_in[5];
    const float* Wv   = (const float*)d_in[6];
    const float* Wo   = (const float*)d_in[7];
    float* Y          = (float*)d_out;

    // workspace layout (bf16 elems)
    bf16* Xb  = (bf16*)d_ws;                       // 4096*2048   = 8388608
    bf16* Wqb = Xb  + (size_t)8388608;             // 2048*2048   = 4194304
    bf16* Wkb = Wqb + (size_t)4194304;             // 512*2048    = 1048576
    bf16* Wvb = Wkb + (size_t)1048576;             // 512*2048    = 1048576
    bf16* Wob = Wvb + (size_t)1048576;             // 2048*2048   = 4194304
    bf16* Qb  = Wob + (size_t)4194304;             // 2*32*2048*64= 8388608
    bf16* Kb  = Qb  + (size_t)8388608;             // 2*8*2048*64 = 2097152
    bf16* Vb  = Kb  + (size_t)2097152;             // 2097152
    bf16* Ob  = Vb  + (size_t)2097152;             // 8388608
    // total ~39.8M bf16 = ~76 MiB

    dim3 blk(256);
    cvt_kernel<<<dim3(1048576 / 256), blk, 0, stream>>>(X,  Xb,  1048576);
    cvt_kernel<<<dim3( 524288 / 256), blk, 0, stream>>>(Wq, Wqb,  524288);
    cvt_kernel<<<dim3( 131072 / 256), blk, 0, stream>>>(Wk, Wkb,  131072);
    cvt_kernel<<<dim3( 131072 / 256), blk, 0, stream>>>(Wv, Wvb,  131072);
    cvt_kernel<<<dim3( 524288 / 256), blk, 0, stream>>>(Wo, Wob,  524288);

    gemm_qkv_kernel<<<dim3(32, 24), blk, 0, stream>>>(Xb, Wqb, Wkb, Wvb,
                                                      cs, sn, Qb, Kb, Vb);
    attn_kernel<<<dim3(S_ / 64, H_, B_), blk, 0, stream>>>(Qb, Kb, Vb, Ob);
    gemm_out_kernel<<<dim3(32, 16), blk, 0, stream>>>(Ob, Wob, Y);
}

// Round 3
// 441.222 us; speedup vs baseline: 2.8814x; 1.1885x over previous
//
#include <hip/hip_runtime.h>
#include <hip/hip_bf16.h>
#include <cstdint>
#include <cstddef>

// Problem constants
#define B_    2
#define S_    2048
#define HID_  2048
#define H_    32
#define HKV_  8
#define DH_   64
#define SCALE_ 0.125f

typedef __bf16 bf16;
typedef bf16  bf16x4 __attribute__((ext_vector_type(4)));
typedef bf16  bf16x8 __attribute__((ext_vector_type(8)));
typedef float f32x4  __attribute__((ext_vector_type(4)));

typedef __attribute__((address_space(3))) uint32_t  lds_u32_t;
typedef __attribute__((address_space(1))) const uint32_t glob_u32_t;

__device__ __forceinline__ void async16(const void* g, void* l) {
    __builtin_amdgcn_global_load_lds((glob_u32_t*)g, (lds_u32_t*)l, 16, 0, 0);
}

__device__ __forceinline__ bf16x8 cvt8(float4 a, float4 b) {
    bf16x8 r;
    r[0] = (bf16)a.x; r[1] = (bf16)a.y; r[2] = (bf16)a.z; r[3] = (bf16)a.w;
    r[4] = (bf16)b.x; r[5] = (bf16)b.y; r[6] = (bf16)b.z; r[7] = (bf16)b.w;
    return r;
}

// ---------------------------------------------------------------------------
__global__ __launch_bounds__(256) void cvt_kernel(
    const float* __restrict__ in, bf16* __restrict__ out, int n8)
{
    const int i = blockIdx.x * 256 + threadIdx.x;
    if (i < n8) {
        float4 a = ((const float4*)in)[2 * i];
        float4 b = ((const float4*)in)[2 * i + 1];
        ((bf16x8*)out)[i] = cvt8(a, b);
    }
}

// ---------------------------------------------------------------------------
// Fused QKV projection GEMM (m97 structure). V written TRANSPOSED (b,hkv,d,s)
// so attention can stage V^T with global_load_lds directly.
// ---------------------------------------------------------------------------
__global__ __launch_bounds__(256) void gemm_qkv_kernel(
    const bf16* __restrict__ A,
    const bf16* __restrict__ Wqb, const bf16* __restrict__ Wkb,
    const bf16* __restrict__ Wvb,
    const float* __restrict__ cs, const float* __restrict__ sn,
    bf16* __restrict__ Qo, bf16* __restrict__ Ko, bf16* __restrict__ Vt)
{
    __shared__ bf16 a_lds[128 * 64];
    __shared__ bf16 b_lds[128 * 64];

    const int tid  = threadIdx.x;
    const int wave = tid >> 6;
    const int lane = tid & 63;
    const int quad = lane >> 4;
    const int l16  = lane & 15;
    const int wm   = wave >> 1;
    const int wn   = wave & 1;
    const int m0   = blockIdx.x * 128;
    const int n0   = blockIdx.y * 128;

    f32x4 acc[4][4];
    #pragma unroll
    for (int mt = 0; mt < 4; ++mt)
        #pragma unroll
        for (int nt = 0; nt < 4; ++nt)
            acc[mt][nt] = (f32x4){0.f, 0.f, 0.f, 0.f};

    int srow[4], sgcol[4];
    const bf16* browp[4];
    #pragma unroll
    for (int i = 0; i < 4; ++i) {
        const int e = tid * 8 + i * 2048;
        srow[i] = e >> 6;
        const int chunk = (e >> 3) & 7;
        sgcol[i] = (chunk ^ (srow[i] & 7)) << 3;
        const int n = n0 + srow[i];
        browp[i] = (n < 2048) ? (Wqb + (size_t)n * HID_)
                 : (n < 2560) ? (Wkb + (size_t)(n - 2048) * HID_)
                              : (Wvb + (size_t)(n - 2560) * HID_);
    }

    for (int k0 = 0; k0 < HID_; k0 += 64) {
        #pragma unroll
        for (int i = 0; i < 4; ++i) {
            async16(A + (size_t)(m0 + srow[i]) * HID_ + k0 + sgcol[i],
                    &a_lds[tid * 8 + i * 2048]);
            async16(browp[i] + k0 + sgcol[i],
                    &b_lds[tid * 8 + i * 2048]);
        }
        __syncthreads();
        #pragma unroll
        for (int ks = 0; ks < 2; ++ks) {
            bf16x8 af[4], bfr[4];
            #pragma unroll
            for (int mt = 0; mt < 4; ++mt) {
                const int row = wm * 64 + mt * 16 + l16;
                const int c = (ks * 4 + quad) ^ (row & 7);
                af[mt] = *(const bf16x8*)(&a_lds[row * 64 + c * 8]);
            }
            #pragma unroll
            for (int nt = 0; nt < 4; ++nt) {
                const int row = wn * 64 + nt * 16 + l16;
                const int c = (ks * 4 + quad) ^ (row & 7);
                bfr[nt] = *(const bf16x8*)(&b_lds[row * 64 + c * 8]);
            }
            #pragma unroll
            for (int mt = 0; mt < 4; ++mt)
                #pragma unroll
                for (int nt = 0; nt < 4; ++nt)
                    acc[mt][nt] = __builtin_amdgcn_mfma_f32_16x16x32_bf16(
                        af[mt], bfr[nt], acc[mt][nt], 0, 0, 0);
        }
        __syncthreads();
    }

    const int nw = n0 + wn * 64;
    const int d  = l16;
    #pragma unroll
    for (int mt = 0; mt < 4; ++mt) {
        #pragma unroll
        for (int r = 0; r < 4; ++r) {
            const int m  = m0 + wm * 64 + mt * 16 + quad * 4 + r;
            const int bb = m >> 11;
            const int ss = m & (S_ - 1);
            const float v0 = acc[mt][0][r], v1 = acc[mt][1][r];
            const float v2 = acc[mt][2][r], v3 = acc[mt][3][r];
            if (nw < 2048) {
                const int h = nw >> 6;
                bf16* dp = Qo + ((size_t)(bb * H_ + h) * S_ + ss) * DH_;
                const float* cp = cs + ((size_t)bb * S_ + ss) * DH_;
                const float* sp = sn + ((size_t)bb * S_ + ss) * DH_;
                dp[ 0 + d] = (bf16)(v0 * cp[ 0 + d] - v2 * sp[ 0 + d]);
                dp[16 + d] = (bf16)(v1 * cp[16 + d] - v3 * sp[16 + d]);
                dp[32 + d] = (bf16)(v2 * cp[32 + d] + v0 * sp[32 + d]);
                dp[48 + d] = (bf16)(v3 * cp[48 + d] + v1 * sp[48 + d]);
            } else if (nw < 2560) {
                const int h = (nw - 2048) >> 6;
                bf16* dp = Ko + ((size_t)(bb * HKV_ + h) * S_ + ss) * DH_;
                const float* cp = cs + ((size_t)bb * S_ + ss) * DH_;
                const float* sp = sn + ((size_t)bb * S_ + ss) * DH_;
                dp[ 0 + d] = (bf16)(v0 * cp[ 0 + d] - v2 * sp[ 0 + d]);
                dp[16 + d] = (bf16)(v1 * cp[16 + d] - v3 * sp[16 + d]);
                dp[32 + d] = (bf16)(v2 * cp[32 + d] + v0 * sp[32 + d]);
                dp[48 + d] = (bf16)(v3 * cp[48 + d] + v1 * sp[48 + d]);
            } else {
                const int h = (nw - 2560) >> 6;
                bf16* dp = Vt + ((size_t)(bb * HKV_ + h) * DH_) * S_ + ss;
                dp[(size_t)( 0 + d) * S_] = (bf16)v0;
                dp[(size_t)(16 + d) * S_] = (bf16)v1;
                dp[(size_t)(32 + d) * S_] = (bf16)v2;
                dp[(size_t)(48 + d) * S_] = (bf16)v3;
            }
        }
    }
}

// ---------------------------------------------------------------------------
// Output projection: Y (4096 x 2048 fp32) = Ob (bf16, (b,s,h*d)) * Wob^T.
// ---------------------------------------------------------------------------
__global__ __launch_bounds__(256) void gemm_out_kernel(
    const bf16* __restrict__ A, const bf16* __restrict__ Wb,
    float* __restrict__ Y)
{
    __shared__ bf16 a_lds[128 * 64];
    __shared__ bf16 b_lds[128 * 64];

    const int tid  = threadIdx.x;
    const int wave = tid >> 6;
    const int lane = tid & 63;
    const int quad = lane >> 4;
    const int l16  = lane & 15;
    const int wm   = wave >> 1;
    const int wn   = wave & 1;
    const int m0   = blockIdx.x * 128;
    const int n0   = blockIdx.y * 128;

    f32x4 acc[4][4];
    #pragma unroll
    for (int mt = 0; mt < 4; ++mt)
        #pragma unroll
        for (int nt = 0; nt < 4; ++nt)
            acc[mt][nt] = (f32x4){0.f, 0.f, 0.f, 0.f};

    int srow[4], sgcol[4];
    #pragma unroll
    for (int i = 0; i < 4; ++i) {
        const int e = tid * 8 + i * 2048;
        srow[i] = e >> 6;
        const int chunk = (e >> 3) & 7;
        sgcol[i] = (chunk ^ (srow[i] & 7)) << 3;
    }

    for (int k0 = 0; k0 < HID_; k0 += 64) {
        #pragma unroll
        for (int i = 0; i < 4; ++i) {
            async16(A + (size_t)(m0 + srow[i]) * HID_ + k0 + sgcol[i],
                    &a_lds[tid * 8 + i * 2048]);
            async16(Wb + (size_t)(n0 + srow[i]) * HID_ + k0 + sgcol[i],
                    &b_lds[tid * 8 + i * 2048]);
        }
        __syncthreads();
        #pragma unroll
        for (int ks = 0; ks < 2; ++ks) {
            bf16x8 af[4], bfr[4];
            #pragma unroll
            for (int mt = 0; mt < 4; ++mt) {
                const int row = wm * 64 + mt * 16 + l16;
                const int c = (ks * 4 + quad) ^ (row & 7);
                af[mt] = *(const bf16x8*)(&a_lds[row * 64 + c * 8]);
            }
            #pragma unroll
            for (int nt = 0; nt < 4; ++nt) {
                const int row = wn * 64 + nt * 16 + l16;
                const int c = (ks * 4 + quad) ^ (row & 7);
                bfr[nt] = *(const bf16x8*)(&b_lds[row * 64 + c * 8]);
            }
            #pragma unroll
            for (int mt = 0; mt < 4; ++mt)
                #pragma unroll
                for (int nt = 0; nt < 4; ++nt)
                    acc[mt][nt] = __builtin_amdgcn_mfma_f32_16x16x32_bf16(
                        af[mt], bfr[nt], acc[mt][nt], 0, 0, 0);
        }
        __syncthreads();
    }

    #pragma unroll
    for (int mt = 0; mt < 4; ++mt)
        #pragma unroll
        for (int nt = 0; nt < 4; ++nt)
            #pragma unroll
            for (int r = 0; r < 4; ++r) {
                const int m = m0 + wm * 64 + mt * 16 + quad * 4 + r;
                const int n = n0 + wn * 64 + nt * 16 + l16;
                Y[(size_t)m * HID_ + n] = acc[mt][nt][r];
            }
}

// ---------------------------------------------------------------------------
// Flash attention v2 (causal, GQA).
// Swapped-operand QK: C = S^T (A=K tile, B=Q frag) so each lane owns ONE q
// (col=l16) and 16 kpos (row=jt*16+quad*4+r). Softmax: in-lane reduce + 2
// shuffles; P packs 4 consecutive kpos -> ds_write_b64; PV A-frag = b128.
// V pre-transposed globally; K and V^T staged via swizzled global_load_lds,
// double-buffered, ONE barrier per 64-k iteration. Block = 128 q rows
// (4 waves x 2 q-tiles). qt reversed so long blocks start first.
// ---------------------------------------------------------------------------
__global__ __launch_bounds__(256, 3) void attn_kernel(
    const bf16* __restrict__ Q, const bf16* __restrict__ K,
    const bf16* __restrict__ Vt, bf16* __restrict__ O)
{
    __shared__ bf16 k_lds[2][64 * 64];
    __shared__ bf16 v_lds[2][64 * 64];
    __shared__ bf16 p_lds[8][16 * 72];   // [wave*2+q2][q=l16][72: 64 kpos + pad]

    const int tid  = threadIdx.x;
    const int wave = tid >> 6;
    const int lane = tid & 63;
    const int quad = lane >> 4;
    const int l16  = lane & 15;
    const int qt = (int)gridDim.x - 1 - (int)blockIdx.x;
    const int h  = blockIdx.y;
    const int b  = blockIdx.z;
    const int hkv = h >> 2;
    const int q0 = qt * 128;

    const bf16* Qg = Q  + (size_t)(b * H_ + h) * S_ * DH_;
    const bf16* Kg = K  + (size_t)(b * HKV_ + hkv) * S_ * DH_;
    const bf16* Vg = Vt + ((size_t)(b * HKV_ + hkv) * DH_) * S_;

    const int qb0 = q0 + wave * 32;

    // Q fragments, B-layout: n=l16 -> q, k=quad*8+j -> dh
    bf16x8 qf[2][2];
    #pragma unroll
    for (int q2 = 0; q2 < 2; ++q2)
        #pragma unroll
        for (int ks = 0; ks < 2; ++ks)
            qf[q2][ks] = *(const bf16x8*)(
                Qg + (size_t)(qb0 + q2 * 16 + l16) * DH_ + ks * 32 + quad * 8);

    f32x4 o_acc[2][4];
    #pragma unroll
    for (int q2 = 0; q2 < 2; ++q2)
        #pragma unroll
        for (int dt = 0; dt < 4; ++dt)
            o_acc[q2][dt] = (f32x4){0.f, 0.f, 0.f, 0.f};
    float m_i[2] = {-__builtin_inff(), -__builtin_inff()};
    float l_i[2] = {0.f, 0.f};

    // staging geometry
    const int srow0  = tid >> 3;
    const int scolsw = ((tid & 7) ^ ((tid >> 3) & 7)) << 3;
    const int nkt = 2 * qt + 2;

    // prefetch tile 0
    #pragma unroll
    for (int i = 0; i < 2; ++i) {
        const int row = srow0 + i * 32;
        async16(Kg + (size_t)row * DH_ + scolsw, &k_lds[0][tid * 8 + i * 2048]);
        async16(Vg + (size_t)row * S_  + scolsw, &v_lds[0][tid * 8 + i * 2048]);
    }
    __syncthreads();

    for (int kt = 0; kt < nkt; ++kt) {
        if (kt + 1 < nkt) {
            bf16* kb = k_lds[(kt + 1) & 1];
            bf16* vb = v_lds[(kt + 1) & 1];
            #pragma unroll
            for (int i = 0; i < 2; ++i) {
                const int row = srow0 + i * 32;
                async16(Kg + (size_t)((kt + 1) * 64 + row) * DH_ + scolsw,
                        kb + tid * 8 + i * 2048);
                async16(Vg + (size_t)row * S_ + (kt + 1) * 64 + scolsw,
                        vb + tid * 8 + i * 2048);
            }
        }

        if (kt * 64 <= qb0 + 31) {   // any q-tile of this wave active
            const bf16* kb = k_lds[kt & 1];
            const bf16* vb = v_lds[kt & 1];
            const int cs8 = l16 & 7;
            bf16x8 kf[4][2], vf[4][2];
            #pragma unroll
            for (int jt = 0; jt < 4; ++jt)
                #pragma unroll
                for (int ks = 0; ks < 2; ++ks) {
                    const int c = ((ks * 4 + quad) ^ cs8) << 3;
                    kf[jt][ks] = *(const bf16x8*)(kb + (jt * 16 + l16) * 64 + c);
                    vf[jt][ks] = *(const bf16x8*)(vb + (jt * 16 + l16) * 64 + c);
                }

            #pragma unroll
            for (int q2 = 0; q2 < 2; ++q2) {
                const int qb = qb0 + q2 * 16;
                if (kt * 64 > qb + 15) continue;   // fully masked
                // scores S^T: 64 kpos x 16 q
                f32x4 s4[4];
                #pragma unroll
                for (int jt = 0; jt < 4; ++jt) {
                    f32x4 a = (f32x4){0.f, 0.f, 0.f, 0.f};
                    #pragma unroll
                    for (int ks = 0; ks < 2; ++ks)
                        a = __builtin_amdgcn_mfma_f32_16x16x32_bf16(
                            kf[jt][ks], qf[q2][ks], a, 0, 0, 0);
                    s4[jt] = a;
                }
                const int qa = qb + l16;
                const bool full = (kt * 64 + 63 <= qb);
                #pragma unroll
                for (int jt = 0; jt < 4; ++jt)
                    #pragma unroll
                    for (int r = 0; r < 4; ++r) {
                        float v = s4[jt][r] * SCALE_;
                        if (!full) {
                            const int kp = kt * 64 + jt * 16 + quad * 4 + r;
                            v = (kp <= qa) ? v : -1e30f;
                        }
                        s4[jt][r] = v;
                    }
                // row stats (q = l16 per lane; combine 4 quads)
                float mx = -1e30f;
                #pragma unroll
                for (int jt = 0; jt < 4; ++jt)
                    #pragma unroll
                    for (int r = 0; r < 4; ++r) mx = fmaxf(mx, s4[jt][r]);
                mx = fmaxf(mx, __shfl_xor(mx, 16));
                mx = fmaxf(mx, __shfl_xor(mx, 32));
                const float mn = fmaxf(m_i[q2], mx);
                const float al = __expf(m_i[q2] - mn);
                m_i[q2] = mn;
                float sm = 0.f;
                #pragma unroll
                for (int jt = 0; jt < 4; ++jt)
                    #pragma unroll
                    for (int r = 0; r < 4; ++r) {
                        const float p = __expf(s4[jt][r] - mn);
                        s4[jt][r] = p;
                        sm += p;
                    }
                sm += __shfl_xor(sm, 16);
                sm += __shfl_xor(sm, 32);
                l_i[q2] = l_i[q2] * al + sm;
                // rescale O (rows q = quad*4+r need alpha from lane quad*4+r)
                float alr[4];
                #pragma unroll
                for (int r = 0; r < 4; ++r) alr[r] = __shfl(al, quad * 4 + r);
                #pragma unroll
                for (int dt = 0; dt < 4; ++dt)
                    #pragma unroll
                    for (int r = 0; r < 4; ++r) o_acc[q2][dt][r] *= alr[r];
                // P -> LDS (4 consecutive kpos per b64)
                bf16* pb = (bf16*)&p_lds[wave * 2 + q2][0];
                #pragma unroll
                for (int jt = 0; jt < 4; ++jt) {
                    bf16x4 pv;
                    #pragma unroll
                    for (int r = 0; r < 4; ++r) pv[r] = (bf16)s4[jt][r];
                    *(bf16x4*)(pb + l16 * 72 + jt * 16 + quad * 4) = pv;
                }
                // PV: A = P (m=q=l16, k=kpos), B = V^T rows (n=d=l16)
                bf16x8 pf[2];
                #pragma unroll
                for (int ks = 0; ks < 2; ++ks)
                    pf[ks] = *(const bf16x8*)(pb + l16 * 72 + ks * 32 + quad * 8);
                #pragma unroll
                for (int dt = 0; dt < 4; ++dt)
                    #pragma unroll
                    for (int ks = 0; ks < 2; ++ks)
                        o_acc[q2][dt] = __builtin_amdgcn_mfma_f32_16x16x32_bf16(
                            pf[ks], vf[dt][ks], o_acc[q2][dt], 0, 0, 0);
            }
        }
        __syncthreads();
    }

    // epilogue: O[b][s][h*64+d]
    #pragma unroll
    for (int q2 = 0; q2 < 2; ++q2) {
        const float inv = 1.f / l_i[q2];
        float ivr[4];
        #pragma unroll
        for (int r = 0; r < 4; ++r) ivr[r] = __shfl(inv, quad * 4 + r);
        #pragma unroll
        for (int dt = 0; dt < 4; ++dt)
            #pragma unroll
            for (int r = 0; r < 4; ++r) {
                const int qa = qb0 + q2 * 16 + quad * 4 + r;
                O[((size_t)(b * S_ + qa) * H_ + h) * DH_ + dt * 16 + l16] =
                    (bf16)(o_acc[q2][dt][r] * ivr[r]);
            }
    }
}

// ---------------------------------------------------------------------------
extern "C" void kernel_launch(void* const* d_in, const int* in_sizes, int n_in,
                              void* d_out, int out_size, void* d_ws, size_t ws_size,
                              hipStream_t stream)
{
    const float* X    = (const float*)d_in[0];
    const float* cs   = (const float*)d_in[1];
    const float* sn   = (const float*)d_in[2];
    const float* Wq   = (const float*)d_in[4];
    const float* Wk   = (const float*)d_in[5];
    const float* Wv   = (const float*)d_in[6];
    const float* Wo   = (const float*)d_in[7];
    float* Y          = (float*)d_out;

    bf16* Xb  = (bf16*)d_ws;                       // 8388608
    bf16* Wqb = Xb  + (size_t)8388608;             // 4194304
    bf16* Wkb = Wqb + (size_t)4194304;             // 1048576
    bf16* Wvb = Wkb + (size_t)1048576;             // 1048576
    bf16* Wob = Wvb + (size_t)1048576;             // 4194304
    bf16* Qb  = Wob + (size_t)4194304;             // 8388608
    bf16* Kb  = Qb  + (size_t)8388608;             // 2097152
    bf16* Vtb = Kb  + (size_t)2097152;             // 2097152 (transposed d,s)
    bf16* Ob  = Vtb + (size_t)2097152;             // 8388608

    dim3 blk(256);
    cvt_kernel<<<dim3(1048576 / 256), blk, 0, stream>>>(X,  Xb,  1048576);
    cvt_kernel<<<dim3( 524288 / 256), blk, 0, stream>>>(Wq, Wqb,  524288);
    cvt_kernel<<<dim3( 131072 / 256), blk, 0, stream>>>(Wk, Wkb,  131072);
    cvt_kernel<<<dim3( 131072 / 256), blk, 0, stream>>>(Wv, Wvb,  131072);
    cvt_kernel<<<dim3( 524288 / 256), blk, 0, stream>>>(Wo, Wob,  524288);

    gemm_qkv_kernel<<<dim3(32, 24), blk, 0, stream>>>(Xb, Wqb, Wkb, Wvb,
                                                      cs, sn, Qb, Kb, Vtb);
    attn_kernel<<<dim3(S_ / 128, H_, B_), blk, 0, stream>>>(Qb, Kb, Vtb, Ob);
    gemm_out_kernel<<<dim3(32, 16), blk, 0, stream>>>(Ob, Wob, Y);
}

// Round 4
// 432.427 us; speedup vs baseline: 2.9400x; 1.0203x over previous
//
#include <hip/hip_runtime.h>
#include <hip/hip_bf16.h>
#include <cstdint>
#include <cstddef>

// Problem constants
#define B_    2
#define S_    2048
#define HID_  2048
#define H_    32
#define HKV_  8
#define DH_   64
// SCALE * log2(e): scores scaled into exp2 domain
#define SC2_  0.1803368801111244f

typedef __bf16 bf16;
typedef bf16  bf16x4 __attribute__((ext_vector_type(4)));
typedef bf16  bf16x8 __attribute__((ext_vector_type(8)));
typedef float f32x4  __attribute__((ext_vector_type(4)));
typedef float f32x16 __attribute__((ext_vector_type(16)));

typedef __attribute__((address_space(3))) uint32_t  lds_u32_t;
typedef __attribute__((address_space(1))) const uint32_t glob_u32_t;

__device__ __forceinline__ void async16(const void* g, void* l) {
    __builtin_amdgcn_global_load_lds((glob_u32_t*)g, (lds_u32_t*)l, 16, 0, 0);
}

__device__ __forceinline__ bf16x8 cvt8(float4 a, float4 b) {
    bf16x8 r;
    r[0] = (bf16)a.x; r[1] = (bf16)a.y; r[2] = (bf16)a.z; r[3] = (bf16)a.w;
    r[4] = (bf16)b.x; r[5] = (bf16)b.y; r[6] = (bf16)b.z; r[7] = (bf16)b.w;
    return r;
}

// ---------------------------------------------------------------------------
// Merged fp32->bf16 convert for all 5 tensors (one launch).
// Region sizes in 8-elem groups: X 1048576 | Wq 524288 | Wk 131072 |
// Wv 131072 | Wo 524288  (total 2359296 groups -> 9216 blocks).
// ---------------------------------------------------------------------------
__global__ __launch_bounds__(256) void cvt_all_kernel(
    const float* __restrict__ X,  const float* __restrict__ Wq,
    const float* __restrict__ Wk, const float* __restrict__ Wv,
    const float* __restrict__ Wo,
    bf16* __restrict__ Xb,  bf16* __restrict__ Wqb, bf16* __restrict__ Wkb,
    bf16* __restrict__ Wvb, bf16* __restrict__ Wob)
{
    const int i = blockIdx.x * 256 + threadIdx.x;
    const float* src; bf16* dst; int off;
    if (i < 1048576)      { src = X;  dst = Xb;  off = i; }
    else if (i < 1572864) { src = Wq; dst = Wqb; off = i - 1048576; }
    else if (i < 1703936) { src = Wk; dst = Wkb; off = i - 1572864; }
    else if (i < 1835008) { src = Wv; dst = Wvb; off = i - 1703936; }
    else                  { src = Wo; dst = Wob; off = i - 1835008; }
    float4 a = ((const float4*)src)[2 * off];
    float4 b = ((const float4*)src)[2 * off + 1];
    ((bf16x8*)dst)[off] = cvt8(a, b);
}

// ---------------------------------------------------------------------------
// Fused QKV projection GEMM (m97 structure). V written TRANSPOSED (b,hkv,d,s).
// ---------------------------------------------------------------------------
__global__ __launch_bounds__(256) void gemm_qkv_kernel(
    const bf16* __restrict__ A,
    const bf16* __restrict__ Wqb, const bf16* __restrict__ Wkb,
    const bf16* __restrict__ Wvb,
    const float* __restrict__ cs, const float* __restrict__ sn,
    bf16* __restrict__ Qo, bf16* __restrict__ Ko, bf16* __restrict__ Vt)
{
    __shared__ bf16 a_lds[128 * 64];
    __shared__ bf16 b_lds[128 * 64];

    const int tid  = threadIdx.x;
    const int wave = tid >> 6;
    const int lane = tid & 63;
    const int quad = lane >> 4;
    const int l16  = lane & 15;
    const int wm   = wave >> 1;
    const int wn   = wave & 1;
    const int m0   = blockIdx.x * 128;
    const int n0   = blockIdx.y * 128;

    f32x4 acc[4][4];
    #pragma unroll
    for (int mt = 0; mt < 4; ++mt)
        #pragma unroll
        for (int nt = 0; nt < 4; ++nt)
            acc[mt][nt] = (f32x4){0.f, 0.f, 0.f, 0.f};

    int srow[4], sgcol[4];
    const bf16* browp[4];
    #pragma unroll
    for (int i = 0; i < 4; ++i) {
        const int e = tid * 8 + i * 2048;
        srow[i] = e >> 6;
        const int chunk = (e >> 3) & 7;
        sgcol[i] = (chunk ^ (srow[i] & 7)) << 3;
        const int n = n0 + srow[i];
        browp[i] = (n < 2048) ? (Wqb + (size_t)n * HID_)
                 : (n < 2560) ? (Wkb + (size_t)(n - 2048) * HID_)
                              : (Wvb + (size_t)(n - 2560) * HID_);
    }

    for (int k0 = 0; k0 < HID_; k0 += 64) {
        #pragma unroll
        for (int i = 0; i < 4; ++i) {
            async16(A + (size_t)(m0 + srow[i]) * HID_ + k0 + sgcol[i],
                    &a_lds[tid * 8 + i * 2048]);
            async16(browp[i] + k0 + sgcol[i],
                    &b_lds[tid * 8 + i * 2048]);
        }
        __syncthreads();
        #pragma unroll
        for (int ks = 0; ks < 2; ++ks) {
            bf16x8 af[4], bfr[4];
            #pragma unroll
            for (int mt = 0; mt < 4; ++mt) {
                const int row = wm * 64 + mt * 16 + l16;
                const int c = (ks * 4 + quad) ^ (row & 7);
                af[mt] = *(const bf16x8*)(&a_lds[row * 64 + c * 8]);
            }
            #pragma unroll
            for (int nt = 0; nt < 4; ++nt) {
                const int row = wn * 64 + nt * 16 + l16;
                const int c = (ks * 4 + quad) ^ (row & 7);
                bfr[nt] = *(const bf16x8*)(&b_lds[row * 64 + c * 8]);
            }
            #pragma unroll
            for (int mt = 0; mt < 4; ++mt)
                #pragma unroll
                for (int nt = 0; nt < 4; ++nt)
                    acc[mt][nt] = __builtin_amdgcn_mfma_f32_16x16x32_bf16(
                        af[mt], bfr[nt], acc[mt][nt], 0, 0, 0);
        }
        __syncthreads();
    }

    const int nw = n0 + wn * 64;
    const int d  = l16;
    #pragma unroll
    for (int mt = 0; mt < 4; ++mt) {
        #pragma unroll
        for (int r = 0; r < 4; ++r) {
            const int m  = m0 + wm * 64 + mt * 16 + quad * 4 + r;
            const int bb = m >> 11;
            const int ss = m & (S_ - 1);
            const float v0 = acc[mt][0][r], v1 = acc[mt][1][r];
            const float v2 = acc[mt][2][r], v3 = acc[mt][3][r];
            if (nw < 2048) {
                const int h = nw >> 6;
                bf16* dp = Qo + ((size_t)(bb * H_ + h) * S_ + ss) * DH_;
                const float* cp = cs + ((size_t)bb * S_ + ss) * DH_;
                const float* sp = sn + ((size_t)bb * S_ + ss) * DH_;
                dp[ 0 + d] = (bf16)(v0 * cp[ 0 + d] - v2 * sp[ 0 + d]);
                dp[16 + d] = (bf16)(v1 * cp[16 + d] - v3 * sp[16 + d]);
                dp[32 + d] = (bf16)(v2 * cp[32 + d] + v0 * sp[32 + d]);
                dp[48 + d] = (bf16)(v3 * cp[48 + d] + v1 * sp[48 + d]);
            } else if (nw < 2560) {
                const int h = (nw - 2048) >> 6;
                bf16* dp = Ko + ((size_t)(bb * HKV_ + h) * S_ + ss) * DH_;
                const float* cp = cs + ((size_t)bb * S_ + ss) * DH_;
                const float* sp = sn + ((size_t)bb * S_ + ss) * DH_;
                dp[ 0 + d] = (bf16)(v0 * cp[ 0 + d] - v2 * sp[ 0 + d]);
                dp[16 + d] = (bf16)(v1 * cp[16 + d] - v3 * sp[16 + d]);
                dp[32 + d] = (bf16)(v2 * cp[32 + d] + v0 * sp[32 + d]);
                dp[48 + d] = (bf16)(v3 * cp[48 + d] + v1 * sp[48 + d]);
            } else {
                const int h = (nw - 2560) >> 6;
                bf16* dp = Vt + ((size_t)(bb * HKV_ + h) * DH_) * S_ + ss;
                dp[(size_t)( 0 + d) * S_] = (bf16)v0;
                dp[(size_t)(16 + d) * S_] = (bf16)v1;
                dp[(size_t)(32 + d) * S_] = (bf16)v2;
                dp[(size_t)(48 + d) * S_] = (bf16)v3;
            }
        }
    }
}

// ---------------------------------------------------------------------------
// Output projection: Y (4096 x 2048 fp32) = Ob (bf16, (b,s,h*d)) * Wob^T.
// ---------------------------------------------------------------------------
__global__ __launch_bounds__(256) void gemm_out_kernel(
    const bf16* __restrict__ A, const bf16* __restrict__ Wb,
    float* __restrict__ Y)
{
    __shared__ bf16 a_lds[128 * 64];
    __shared__ bf16 b_lds[128 * 64];

    const int tid  = threadIdx.x;
    const int wave = tid >> 6;
    const int lane = tid & 63;
    const int quad = lane >> 4;
    const int l16  = lane & 15;
    const int wm   = wave >> 1;
    const int wn   = wave & 1;
    const int m0   = blockIdx.x * 128;
    const int n0   = blockIdx.y * 128;

    f32x4 acc[4][4];
    #pragma unroll
    for (int mt = 0; mt < 4; ++mt)
        #pragma unroll
        for (int nt = 0; nt < 4; ++nt)
            acc[mt][nt] = (f32x4){0.f, 0.f, 0.f, 0.f};

    int srow[4], sgcol[4];
    #pragma unroll
    for (int i = 0; i < 4; ++i) {
        const int e = tid * 8 + i * 2048;
        srow[i] = e >> 6;
        const int chunk = (e >> 3) & 7;
        sgcol[i] = (chunk ^ (srow[i] & 7)) << 3;
    }

    for (int k0 = 0; k0 < HID_; k0 += 64) {
        #pragma unroll
        for (int i = 0; i < 4; ++i) {
            async16(A + (size_t)(m0 + srow[i]) * HID_ + k0 + sgcol[i],
                    &a_lds[tid * 8 + i * 2048]);
            async16(Wb + (size_t)(n0 + srow[i]) * HID_ + k0 + sgcol[i],
                    &b_lds[tid * 8 + i * 2048]);
        }
        __syncthreads();
        #pragma unroll
        for (int ks = 0; ks < 2; ++ks) {
            bf16x8 af[4], bfr[4];
            #pragma unroll
            for (int mt = 0; mt < 4; ++mt) {
                const int row = wm * 64 + mt * 16 + l16;
                const int c = (ks * 4 + quad) ^ (row & 7);
                af[mt] = *(const bf16x8*)(&a_lds[row * 64 + c * 8]);
            }
            #pragma unroll
            for (int nt = 0; nt < 4; ++nt) {
                const int row = wn * 64 + nt * 16 + l16;
                const int c = (ks * 4 + quad) ^ (row & 7);
                bfr[nt] = *(const bf16x8*)(&b_lds[row * 64 + c * 8]);
            }
            #pragma unroll
            for (int mt = 0; mt < 4; ++mt)
                #pragma unroll
                for (int nt = 0; nt < 4; ++nt)
                    acc[mt][nt] = __builtin_amdgcn_mfma_f32_16x16x32_bf16(
                        af[mt], bfr[nt], acc[mt][nt], 0, 0, 0);
        }
        __syncthreads();
    }

    #pragma unroll
    for (int mt = 0; mt < 4; ++mt)
        #pragma unroll
        for (int nt = 0; nt < 4; ++nt)
            #pragma unroll
            for (int r = 0; r < 4; ++r) {
                const int m = m0 + wm * 64 + mt * 16 + quad * 4 + r;
                const int n = n0 + wn * 64 + nt * 16 + l16;
                Y[(size_t)m * HID_ + n] = acc[mt][nt][r];
            }
}

// ---------------------------------------------------------------------------
// Flash attention v3 (causal, GQA), 32x32x16 MFMA.
// QK swapped (A=K, B=Q) -> S^T: C col=lane&31=q, row=kpos.
// PV swapped (A=V^T, B=P^T) -> O^T: C col=lane&31=q, row=d.
//   => m/l/alpha/normalize all SAME-LANE (q = lane&31); stats need only
//      one shfl_xor(32) each (kpos split across lane halves).
// Fragment layouts (32x32x16_bf16): A[m=lane&31][k=(lane>>5)*8+j],
//   B[k=(lane>>5)*8+j][n=lane&31], C col=lane&31, row=(r&3)+8*(r>>2)+4*(lane>>5).
// K/V^T double-buffered LDS via global_load_lds, 1 barrier/iter.
// P round-trips per-wave LDS (stride 72: b64 writes / b128 reads, 16B-aligned).
// Block = 128 q (4 waves x 32 q). qt reversed so long blocks start first.
// ---------------------------------------------------------------------------
__global__ __launch_bounds__(256) void attn_kernel(
    const bf16* __restrict__ Q, const bf16* __restrict__ K,
    const bf16* __restrict__ Vt, bf16* __restrict__ O)
{
    __shared__ bf16 k_lds[2][64 * 64];
    __shared__ bf16 v_lds[2][64 * 64];
    __shared__ bf16 p_lds[4][32 * 72];

    const int tid  = threadIdx.x;
    const int wave = tid >> 6;
    const int lane = tid & 63;
    const int l32  = lane & 31;
    const int half = lane >> 5;
    const int qt = (int)gridDim.x - 1 - (int)blockIdx.x;
    const int h  = blockIdx.y;
    const int b  = blockIdx.z;
    const int hkv = h >> 2;
    const int q0 = qt * 128;
    const int qb0 = q0 + wave * 32;

    const bf16* Qg = Q  + (size_t)(b * H_ + h) * S_ * DH_;
    const bf16* Kg = K  + (size_t)(b * HKV_ + hkv) * S_ * DH_;
    const bf16* Vg = Vt + ((size_t)(b * HKV_ + hkv) * DH_) * S_;

    // Q fragments, B-layout: n=l32 -> q, k=c*16 + half*8 + j -> dh
    bf16x8 qf[4];
    #pragma unroll
    for (int c = 0; c < 4; ++c)
        qf[c] = *(const bf16x8*)(Qg + (size_t)(qb0 + l32) * DH_ + c * 16 + half * 8);

    f32x16 o_acc[2];
    #pragma unroll
    for (int dt = 0; dt < 2; ++dt)
        #pragma unroll
        for (int e = 0; e < 16; ++e) o_acc[dt][e] = 0.f;
    float m_i = -1e30f, l_i = 0.f;

    const int srow0  = tid >> 3;
    const int scolsw = ((tid & 7) ^ ((tid >> 3) & 7)) << 3;
    const int nkt = 2 * qt + 2;

    // prefetch tile 0
    #pragma unroll
    for (int i = 0; i < 2; ++i) {
        const int row = srow0 + i * 32;
        async16(Kg + (size_t)row * DH_ + scolsw, &k_lds[0][tid * 8 + i * 2048]);
        async16(Vg + (size_t)row * S_  + scolsw, &v_lds[0][tid * 8 + i * 2048]);
    }
    __syncthreads();

    for (int kt = 0; kt < nkt; ++kt) {
        if (kt + 1 < nkt) {
            bf16* kb = k_lds[(kt + 1) & 1];
            bf16* vb = v_lds[(kt + 1) & 1];
            #pragma unroll
            for (int i = 0; i < 2; ++i) {
                const int row = srow0 + i * 32;
                async16(Kg + (size_t)((kt + 1) * 64 + row) * DH_ + scolsw,
                        kb + tid * 8 + i * 2048);
                async16(Vg + (size_t)row * S_ + (kt + 1) * 64 + scolsw,
                        vb + tid * 8 + i * 2048);
            }
        }

        if (kt * 64 <= qb0 + 31) {
            const bf16* kb = k_lds[kt & 1];
            const bf16* vb = v_lds[kt & 1];
            // fragments: rows = t*32 + l32, 16B-chunk id = 2*c + half (swizzled)
            bf16x8 kf[2][4], vf[2][4];
            #pragma unroll
            for (int t = 0; t < 2; ++t)
                #pragma unroll
                for (int c = 0; c < 4; ++c) {
                    const int row = t * 32 + l32;
                    const int col = ((2 * c + half) ^ (row & 7)) << 3;
                    kf[t][c] = *(const bf16x8*)(kb + row * 64 + col);
                    vf[t][c] = *(const bf16x8*)(vb + row * 64 + col);
                }

            // scores S^T: 64 kpos x 32 q (2 C-tiles)
            f32x16 s[2];
            #pragma unroll
            for (int t = 0; t < 2; ++t) {
                f32x16 a;
                #pragma unroll
                for (int e = 0; e < 16; ++e) a[e] = 0.f;
                #pragma unroll
                for (int c = 0; c < 4; ++c)
                    a = __builtin_amdgcn_mfma_f32_32x32x16_bf16(
                        kf[t][c], qf[c], a, 0, 0, 0);
                s[t] = a;
            }

            // scale (exp2 domain) + causal mask
            const int qa = qb0 + l32;
            const bool full = (kt * 64 + 63 <= qb0);
            #pragma unroll
            for (int t = 0; t < 2; ++t)
                #pragma unroll
                for (int e = 0; e < 16; ++e) {
                    float v = s[t][e] * SC2_;
                    if (!full) {
                        const int kp = kt * 64 + t * 32 + (e & 3) + 8 * (e >> 2) + 4 * half;
                        v = (kp <= qa) ? v : -1e30f;
                    }
                    s[t][e] = v;
                }

            // stats: per-lane q; combine halves with one xor-32 shuffle
            float mx = -1e30f;
            #pragma unroll
            for (int t = 0; t < 2; ++t)
                #pragma unroll
                for (int e = 0; e < 16; ++e) mx = fmaxf(mx, s[t][e]);
            mx = fmaxf(mx, __shfl_xor(mx, 32));
            const float mn = fmaxf(m_i, mx);
            const float al = exp2f(m_i - mn);
            m_i = mn;
            float sm = 0.f;
            #pragma unroll
            for (int t = 0; t < 2; ++t)
                #pragma unroll
                for (int e = 0; e < 16; ++e) {
                    const float p = exp2f(s[t][e] - mn);
                    s[t][e] = p;
                    sm += p;
                }
            sm += __shfl_xor(sm, 32);
            l_i = l_i * al + sm;
            #pragma unroll
            for (int dt = 0; dt < 2; ++dt)
                #pragma unroll
                for (int e = 0; e < 16; ++e) o_acc[dt][e] *= al;

            // P -> per-wave LDS: C-layout -> B-layout (P^T). 4 consecutive
            // kpos per b64: kpos = t*32 + g*8 + half*4 + (0..3), col q=l32.
            bf16* pb = (bf16*)&p_lds[wave][0];
            #pragma unroll
            for (int t = 0; t < 2; ++t)
                #pragma unroll
                for (int g = 0; g < 4; ++g) {
                    bf16x4 pv;
                    #pragma unroll
                    for (int r = 0; r < 4; ++r) pv[r] = (bf16)s[t][g * 4 + r];
                    *(bf16x4*)(pb + l32 * 72 + t * 32 + g * 8 + half * 4) = pv;
                }
            bf16x8 pf[4];
            #pragma unroll
            for (int c = 0; c < 4; ++c)
                pf[c] = *(const bf16x8*)(pb + l32 * 72 + c * 16 + half * 8);

            // O^T += V^T * P^T : A=vf (m=d), B=pf (n=q)
            #pragma unroll
            for (int dt = 0; dt < 2; ++dt)
                #pragma unroll
                for (int c = 0; c < 4; ++c)
                    o_acc[dt] = __builtin_amdgcn_mfma_f32_32x32x16_bf16(
                        vf[dt][c], pf[c], o_acc[dt], 0, 0, 0);
        }
        __syncthreads();
    }

    // epilogue: O^T C-layout -> Ob (b, s, h*64+d); q = l32 (same lane as l_i)
    const float inv = 1.f / l_i;
    const int qa = qb0 + l32;
    bf16* op = O + ((size_t)(b * S_ + qa) * H_ + h) * DH_;
    #pragma unroll
    for (int dt = 0; dt < 2; ++dt)
        #pragma unroll
        for (int g = 0; g < 4; ++g) {
            bf16x4 ov;
            #pragma unroll
            for (int r = 0; r < 4; ++r) ov[r] = (bf16)(o_acc[dt][g * 4 + r] * inv);
            *(bf16x4*)(op + dt * 32 + g * 8 + half * 4) = ov;
        }
}

// ---------------------------------------------------------------------------
extern "C" void kernel_launch(void* const* d_in, const int* in_sizes, int n_in,
                              void* d_out, int out_size, void* d_ws, size_t ws_size,
                              hipStream_t stream)
{
    const float* X    = (const float*)d_in[0];
    const float* cs   = (const float*)d_in[1];
    const float* sn   = (const float*)d_in[2];
    const float* Wq   = (const float*)d_in[4];
    const float* Wk   = (const float*)d_in[5];
    const float* Wv   = (const float*)d_in[6];
    const float* Wo   = (const float*)d_in[7];
    float* Y          = (float*)d_out;

    bf16* Xb  = (bf16*)d_ws;                       // 8388608
    bf16* Wqb = Xb  + (size_t)8388608;             // 4194304
    bf16* Wkb = Wqb + (size_t)4194304;             // 1048576
    bf16* Wvb = Wkb + (size_t)1048576;             // 1048576
    bf16* Wob = Wvb + (size_t)1048576;             // 4194304
    bf16* Qb  = Wob + (size_t)4194304;             // 8388608
    bf16* Kb  = Qb  + (size_t)8388608;             // 2097152
    bf16* Vtb = Kb  + (size_t)2097152;             // 2097152 (transposed d,s)
    bf16* Ob  = Vtb + (size_t)2097152;             // 8388608

    dim3 blk(256);
    cvt_all_kernel<<<dim3(9216), blk, 0, stream>>>(X, Wq, Wk, Wv, Wo,
                                                   Xb, Wqb, Wkb, Wvb, Wob);
    gemm_qkv_kernel<<<dim3(32, 24), blk, 0, stream>>>(Xb, Wqb, Wkb, Wvb,
                                                      cs, sn, Qb, Kb, Vtb);
    attn_kernel<<<dim3(S_ / 128, H_, B_), blk, 0, stream>>>(Qb, Kb, Vtb, Ob);
    gemm_out_kernel<<<dim3(32, 16), blk, 0, stream>>>(Ob, Wob, Y);
}

// Round 5
// 371.750 us; speedup vs baseline: 3.4199x; 1.1632x over previous
//
#include <hip/hip_runtime.h>
#include <hip/hip_bf16.h>
#include <cstdint>
#include <cstddef>

// Problem constants
#define B_    2
#define S_    2048
#define HID_  2048
#define H_    32
#define HKV_  8
#define DH_   64
// SCALE * log2(e): scores scaled into exp2 domain
#define SC2_  0.1803368801111244f

typedef __bf16 bf16;
typedef bf16  bf16x2 __attribute__((ext_vector_type(2)));
typedef bf16  bf16x4 __attribute__((ext_vector_type(4)));
typedef bf16  bf16x8 __attribute__((ext_vector_type(8)));
typedef float f32x4  __attribute__((ext_vector_type(4)));
typedef float f32x16 __attribute__((ext_vector_type(16)));

typedef __attribute__((address_space(3))) uint32_t  lds_u32_t;
typedef __attribute__((address_space(1))) const uint32_t glob_u32_t;

__device__ __forceinline__ void async16(const void* g, void* l) {
    __builtin_amdgcn_global_load_lds((glob_u32_t*)g, (lds_u32_t*)l, 16, 0, 0);
}

__device__ __forceinline__ bf16x8 cvt8(float4 a, float4 b) {
    bf16x8 r;
    r[0] = (bf16)a.x; r[1] = (bf16)a.y; r[2] = (bf16)a.z; r[3] = (bf16)a.w;
    r[4] = (bf16)b.x; r[5] = (bf16)b.y; r[6] = (bf16)b.z; r[7] = (bf16)b.w;
    return r;
}

__device__ __forceinline__ uint32_t pkbf(float a, float b) {
    bf16x2 t; t[0] = (bf16)a; t[1] = (bf16)b;
    return __builtin_bit_cast(uint32_t, t);
}
__device__ __forceinline__ bf16x8 mk8(uint32_t a, uint32_t b, uint32_t c, uint32_t d) {
    union { uint32_t u[4]; bf16x8 v; } t;
    t.u[0] = a; t.u[1] = b; t.u[2] = c; t.u[3] = d;
    return t.v;
}

// ---------------------------------------------------------------------------
// Merged fp32->bf16 convert for all 5 tensors (one launch).
// ---------------------------------------------------------------------------
__global__ __launch_bounds__(256) void cvt_all_kernel(
    const float* __restrict__ X,  const float* __restrict__ Wq,
    const float* __restrict__ Wk, const float* __restrict__ Wv,
    const float* __restrict__ Wo,
    bf16* __restrict__ Xb,  bf16* __restrict__ Wqb, bf16* __restrict__ Wkb,
    bf16* __restrict__ Wvb, bf16* __restrict__ Wob)
{
    const int i = blockIdx.x * 256 + threadIdx.x;
    const float* src; bf16* dst; int off;
    if (i < 1048576)      { src = X;  dst = Xb;  off = i; }
    else if (i < 1572864) { src = Wq; dst = Wqb; off = i - 1048576; }
    else if (i < 1703936) { src = Wk; dst = Wkb; off = i - 1572864; }
    else if (i < 1835008) { src = Wv; dst = Wvb; off = i - 1703936; }
    else                  { src = Wo; dst = Wob; off = i - 1835008; }
    float4 a = ((const float4*)src)[2 * off];
    float4 b = ((const float4*)src)[2 * off + 1];
    ((bf16x8*)dst)[off] = cvt8(a, b);
}

// ---------------------------------------------------------------------------
// Fused QKV projection GEMM (m97 structure). V written TRANSPOSED (b,hkv,d,s).
// ---------------------------------------------------------------------------
__global__ __launch_bounds__(256) void gemm_qkv_kernel(
    const bf16* __restrict__ A,
    const bf16* __restrict__ Wqb, const bf16* __restrict__ Wkb,
    const bf16* __restrict__ Wvb,
    const float* __restrict__ cs, const float* __restrict__ sn,
    bf16* __restrict__ Qo, bf16* __restrict__ Ko, bf16* __restrict__ Vt)
{
    __shared__ bf16 a_lds[128 * 64];
    __shared__ bf16 b_lds[128 * 64];

    const int tid  = threadIdx.x;
    const int wave = tid >> 6;
    const int lane = tid & 63;
    const int quad = lane >> 4;
    const int l16  = lane & 15;
    const int wm   = wave >> 1;
    const int wn   = wave & 1;
    const int m0   = blockIdx.x * 128;
    const int n0   = blockIdx.y * 128;

    f32x4 acc[4][4];
    #pragma unroll
    for (int mt = 0; mt < 4; ++mt)
        #pragma unroll
        for (int nt = 0; nt < 4; ++nt)
            acc[mt][nt] = (f32x4){0.f, 0.f, 0.f, 0.f};

    int srow[4], sgcol[4];
    const bf16* browp[4];
    #pragma unroll
    for (int i = 0; i < 4; ++i) {
        const int e = tid * 8 + i * 2048;
        srow[i] = e >> 6;
        const int chunk = (e >> 3) & 7;
        sgcol[i] = (chunk ^ (srow[i] & 7)) << 3;
        const int n = n0 + srow[i];
        browp[i] = (n < 2048) ? (Wqb + (size_t)n * HID_)
                 : (n < 2560) ? (Wkb + (size_t)(n - 2048) * HID_)
                              : (Wvb + (size_t)(n - 2560) * HID_);
    }

    for (int k0 = 0; k0 < HID_; k0 += 64) {
        #pragma unroll
        for (int i = 0; i < 4; ++i) {
            async16(A + (size_t)(m0 + srow[i]) * HID_ + k0 + sgcol[i],
                    &a_lds[tid * 8 + i * 2048]);
            async16(browp[i] + k0 + sgcol[i],
                    &b_lds[tid * 8 + i * 2048]);
        }
        __syncthreads();
        #pragma unroll
        for (int ks = 0; ks < 2; ++ks) {
            bf16x8 af[4], bfr[4];
            #pragma unroll
            for (int mt = 0; mt < 4; ++mt) {
                const int row = wm * 64 + mt * 16 + l16;
                const int c = (ks * 4 + quad) ^ (row & 7);
                af[mt] = *(const bf16x8*)(&a_lds[row * 64 + c * 8]);
            }
            #pragma unroll
            for (int nt = 0; nt < 4; ++nt) {
                const int row = wn * 64 + nt * 16 + l16;
                const int c = (ks * 4 + quad) ^ (row & 7);
                bfr[nt] = *(const bf16x8*)(&b_lds[row * 64 + c * 8]);
            }
            #pragma unroll
            for (int mt = 0; mt < 4; ++mt)
                #pragma unroll
                for (int nt = 0; nt < 4; ++nt)
                    acc[mt][nt] = __builtin_amdgcn_mfma_f32_16x16x32_bf16(
                        af[mt], bfr[nt], acc[mt][nt], 0, 0, 0);
        }
        __syncthreads();
    }

    const int nw = n0 + wn * 64;
    const int d  = l16;
    #pragma unroll
    for (int mt = 0; mt < 4; ++mt) {
        #pragma unroll
        for (int r = 0; r < 4; ++r) {
            const int m  = m0 + wm * 64 + mt * 16 + quad * 4 + r;
            const int bb = m >> 11;
            const int ss = m & (S_ - 1);
            const float v0 = acc[mt][0][r], v1 = acc[mt][1][r];
            const float v2 = acc[mt][2][r], v3 = acc[mt][3][r];
            if (nw < 2048) {
                const int h = nw >> 6;
                bf16* dp = Qo + ((size_t)(bb * H_ + h) * S_ + ss) * DH_;
                const float* cp = cs + ((size_t)bb * S_ + ss) * DH_;
                const float* sp = sn + ((size_t)bb * S_ + ss) * DH_;
                dp[ 0 + d] = (bf16)(v0 * cp[ 0 + d] - v2 * sp[ 0 + d]);
                dp[16 + d] = (bf16)(v1 * cp[16 + d] - v3 * sp[16 + d]);
                dp[32 + d] = (bf16)(v2 * cp[32 + d] + v0 * sp[32 + d]);
                dp[48 + d] = (bf16)(v3 * cp[48 + d] + v1 * sp[48 + d]);
            } else if (nw < 2560) {
                const int h = (nw - 2048) >> 6;
                bf16* dp = Ko + ((size_t)(bb * HKV_ + h) * S_ + ss) * DH_;
                const float* cp = cs + ((size_t)bb * S_ + ss) * DH_;
                const float* sp = sn + ((size_t)bb * S_ + ss) * DH_;
                dp[ 0 + d] = (bf16)(v0 * cp[ 0 + d] - v2 * sp[ 0 + d]);
                dp[16 + d] = (bf16)(v1 * cp[16 + d] - v3 * sp[16 + d]);
                dp[32 + d] = (bf16)(v2 * cp[32 + d] + v0 * sp[32 + d]);
                dp[48 + d] = (bf16)(v3 * cp[48 + d] + v1 * sp[48 + d]);
            } else {
                const int h = (nw - 2560) >> 6;
                bf16* dp = Vt + ((size_t)(bb * HKV_ + h) * DH_) * S_ + ss;
                dp[(size_t)( 0 + d) * S_] = (bf16)v0;
                dp[(size_t)(16 + d) * S_] = (bf16)v1;
                dp[(size_t)(32 + d) * S_] = (bf16)v2;
                dp[(size_t)(48 + d) * S_] = (bf16)v3;
            }
        }
    }
}

// ---------------------------------------------------------------------------
// Output projection: Y (4096 x 2048 fp32) = Ob (bf16, (b,s,h*d)) * Wob^T.
// ---------------------------------------------------------------------------
__global__ __launch_bounds__(256) void gemm_out_kernel(
    const bf16* __restrict__ A, const bf16* __restrict__ Wb,
    float* __restrict__ Y)
{
    __shared__ bf16 a_lds[128 * 64];
    __shared__ bf16 b_lds[128 * 64];

    const int tid  = threadIdx.x;
    const int wave = tid >> 6;
    const int lane = tid & 63;
    const int quad = lane >> 4;
    const int l16  = lane & 15;
    const int wm   = wave >> 1;
    const int wn   = wave & 1;
    const int m0   = blockIdx.x * 128;
    const int n0   = blockIdx.y * 128;

    f32x4 acc[4][4];
    #pragma unroll
    for (int mt = 0; mt < 4; ++mt)
        #pragma unroll
        for (int nt = 0; nt < 4; ++nt)
            acc[mt][nt] = (f32x4){0.f, 0.f, 0.f, 0.f};

    int srow[4], sgcol[4];
    #pragma unroll
    for (int i = 0; i < 4; ++i) {
        const int e = tid * 8 + i * 2048;
        srow[i] = e >> 6;
        const int chunk = (e >> 3) & 7;
        sgcol[i] = (chunk ^ (srow[i] & 7)) << 3;
    }

    for (int k0 = 0; k0 < HID_; k0 += 64) {
        #pragma unroll
        for (int i = 0; i < 4; ++i) {
            async16(A + (size_t)(m0 + srow[i]) * HID_ + k0 + sgcol[i],
                    &a_lds[tid * 8 + i * 2048]);
            async16(Wb + (size_t)(n0 + srow[i]) * HID_ + k0 + sgcol[i],
                    &b_lds[tid * 8 + i * 2048]);
        }
        __syncthreads();
        #pragma unroll
        for (int ks = 0; ks < 2; ++ks) {
            bf16x8 af[4], bfr[4];
            #pragma unroll
            for (int mt = 0; mt < 4; ++mt) {
                const int row = wm * 64 + mt * 16 + l16;
                const int c = (ks * 4 + quad) ^ (row & 7);
                af[mt] = *(const bf16x8*)(&a_lds[row * 64 + c * 8]);
            }
            #pragma unroll
            for (int nt = 0; nt < 4; ++nt) {
                const int row = wn * 64 + nt * 16 + l16;
                const int c = (ks * 4 + quad) ^ (row & 7);
                bfr[nt] = *(const bf16x8*)(&b_lds[row * 64 + c * 8]);
            }
            #pragma unroll
            for (int mt = 0; mt < 4; ++mt)
                #pragma unroll
                for (int nt = 0; nt < 4; ++nt)
                    acc[mt][nt] = __builtin_amdgcn_mfma_f32_16x16x32_bf16(
                        af[mt], bfr[nt], acc[mt][nt], 0, 0, 0);
        }
        __syncthreads();
    }

    #pragma unroll
    for (int mt = 0; mt < 4; ++mt)
        #pragma unroll
        for (int nt = 0; nt < 4; ++nt)
            #pragma unroll
            for (int r = 0; r < 4; ++r) {
                const int m = m0 + wm * 64 + mt * 16 + quad * 4 + r;
                const int n = n0 + wn * 64 + nt * 16 + l16;
                Y[(size_t)m * HID_ + n] = acc[mt][nt][r];
            }
}

// ---------------------------------------------------------------------------
// Flash attention v4 (causal, GQA), 32x32x16 MFMA.
// QK swapped (A=K, B=Q) -> S^T (col=q=lane&31); PV swapped (A=V^T, B=P^T) ->
// O^T (col=q) => all softmax state same-lane; stats need 1 shfl_xor(32).
// P C-layout -> B-layout via cross-half shfl_xor register exchange (no LDS).
// K/V^T double-buffered LDS (32 KB total), 1 barrier/iter.
// Load balance: block processes q-tile pair (qt, 15-qt) -> uniform 34 iters.
// Diagonal sub-tile skip for the upper 32-kpos half.
// ---------------------------------------------------------------------------
__global__ __launch_bounds__(256) void attn_kernel(
    const bf16* __restrict__ Q, const bf16* __restrict__ K,
    const bf16* __restrict__ Vt, bf16* __restrict__ O)
{
    __shared__ bf16 k_lds[2][64 * 64];
    __shared__ bf16 v_lds[2][64 * 64];

    const int tid  = threadIdx.x;
    const int wave = tid >> 6;
    const int lane = tid & 63;
    const int l32  = lane & 31;
    const int half = lane >> 5;
    const int h  = blockIdx.y;
    const int b  = blockIdx.z;
    const int hkv = h >> 2;

    const bf16* Qg = Q  + (size_t)(b * H_ + h) * S_ * DH_;
    const bf16* Kg = K  + (size_t)(b * HKV_ + hkv) * S_ * DH_;
    const bf16* Vg = Vt + ((size_t)(b * HKV_ + hkv) * DH_) * S_;

    const int srow0  = tid >> 3;
    const int scolsw = ((tid & 7) ^ ((tid >> 3) & 7)) << 3;

    #pragma unroll 1
    for (int ph = 0; ph < 2; ++ph) {
        const int qt  = ph == 0 ? (int)blockIdx.x : (15 - (int)blockIdx.x);
        const int q0  = qt * 128;
        const int qb0 = q0 + wave * 32;
        const int qa  = qb0 + l32;

        // Q fragments, B-layout: n=l32 -> q, k = c*16 + half*8 + j -> dh
        bf16x8 qf[4];
        #pragma unroll
        for (int c = 0; c < 4; ++c)
            qf[c] = *(const bf16x8*)(Qg + (size_t)(qb0 + l32) * DH_ + c * 16 + half * 8);

        f32x16 o_acc[2];
        #pragma unroll
        for (int dt = 0; dt < 2; ++dt)
            #pragma unroll
            for (int e = 0; e < 16; ++e) o_acc[dt][e] = 0.f;
        float m_i = -1e30f, l_i = 0.f;

        const int nkt = 2 * qt + 2;

        // prefetch tile 0
        #pragma unroll
        for (int i = 0; i < 2; ++i) {
            const int row = srow0 + i * 32;
            async16(Kg + (size_t)row * DH_ + scolsw, &k_lds[0][tid * 8 + i * 2048]);
            async16(Vg + (size_t)row * S_  + scolsw, &v_lds[0][tid * 8 + i * 2048]);
        }
        __syncthreads();

        for (int kt = 0; kt < nkt; ++kt) {
            if (kt + 1 < nkt) {
                bf16* kb = k_lds[(kt + 1) & 1];
                bf16* vb = v_lds[(kt + 1) & 1];
                #pragma unroll
                for (int i = 0; i < 2; ++i) {
                    const int row = srow0 + i * 32;
                    async16(Kg + (size_t)((kt + 1) * 64 + row) * DH_ + scolsw,
                            kb + tid * 8 + i * 2048);
                    async16(Vg + (size_t)row * S_ + (kt + 1) * 64 + scolsw,
                            vb + tid * 8 + i * 2048);
                }
            }

            if (kt * 64 <= qb0 + 31) {
                const bf16* kb = k_lds[kt & 1];
                const bf16* vb = v_lds[kt & 1];
                const bool act1 = (kt * 64 + 32) <= (qb0 + 31);

                // V^T A-frags: vf[dt][c] = V^T[dt*32+l32][c*16+half*8 ..+8]
                bf16x8 vf[2][4];
                #pragma unroll
                for (int dt = 0; dt < 2; ++dt)
                    #pragma unroll
                    for (int c = 0; c < 4; ++c) {
                        const int row = dt * 32 + l32;
                        const int col = ((2 * c + half) ^ (row & 7)) << 3;
                        vf[dt][c] = *(const bf16x8*)(vb + row * 64 + col);
                    }

                // scores tile 0 (kpos kt*64 .. +31)
                f32x16 s0, s1;
                {
                    bf16x8 kf[4];
                    #pragma unroll
                    for (int c = 0; c < 4; ++c) {
                        const int row = l32;
                        const int col = ((2 * c + half) ^ (row & 7)) << 3;
                        kf[c] = *(const bf16x8*)(kb + row * 64 + col);
                    }
                    f32x16 a;
                    #pragma unroll
                    for (int e = 0; e < 16; ++e) a[e] = 0.f;
                    #pragma unroll
                    for (int c = 0; c < 4; ++c)
                        a = __builtin_amdgcn_mfma_f32_32x32x16_bf16(kf[c], qf[c], a, 0, 0, 0);
                    s0 = a;
                }
                if (act1) {
                    bf16x8 kf[4];
                    #pragma unroll
                    for (int c = 0; c < 4; ++c) {
                        const int row = 32 + l32;
                        const int col = ((2 * c + half) ^ (row & 7)) << 3;
                        kf[c] = *(const bf16x8*)(kb + row * 64 + col);
                    }
                    f32x16 a;
                    #pragma unroll
                    for (int e = 0; e < 16; ++e) a[e] = 0.f;
                    #pragma unroll
                    for (int c = 0; c < 4; ++c)
                        a = __builtin_amdgcn_mfma_f32_32x32x16_bf16(kf[c], qf[c], a, 0, 0, 0);
                    s1 = a;
                }

                // scale + causal mask
                {
                    const bool full0 = (kt * 64 + 31) <= qb0;
                    #pragma unroll
                    for (int e = 0; e < 16; ++e) {
                        float v = s0[e] * SC2_;
                        if (!full0) {
                            const int kp = kt * 64 + (e & 3) + 8 * (e >> 2) + 4 * half;
                            v = (kp <= qa) ? v : -1e30f;
                        }
                        s0[e] = v;
                    }
                }
                if (act1) {
                    const bool full1 = (kt * 64 + 63) <= qb0;
                    #pragma unroll
                    for (int e = 0; e < 16; ++e) {
                        float v = s1[e] * SC2_;
                        if (!full1) {
                            const int kp = kt * 64 + 32 + (e & 3) + 8 * (e >> 2) + 4 * half;
                            v = (kp <= qa) ? v : -1e30f;
                        }
                        s1[e] = v;
                    }
                }

                // stats (per-lane q, combine halves with one xor-32)
                float mx = -1e30f;
                #pragma unroll
                for (int e = 0; e < 16; ++e) mx = fmaxf(mx, s0[e]);
                if (act1)
                    #pragma unroll
                    for (int e = 0; e < 16; ++e) mx = fmaxf(mx, s1[e]);
                mx = fmaxf(mx, __shfl_xor(mx, 32));
                const float mn = fmaxf(m_i, mx);
                const float al = exp2f(m_i - mn);
                m_i = mn;
                float sm = 0.f;
                #pragma unroll
                for (int e = 0; e < 16; ++e) {
                    const float p = exp2f(s0[e] - mn);
                    s0[e] = p; sm += p;
                }
                if (act1)
                    #pragma unroll
                    for (int e = 0; e < 16; ++e) {
                        const float p = exp2f(s1[e] - mn);
                        s1[e] = p; sm += p;
                    }
                sm += __shfl_xor(sm, 32);
                l_i = l_i * al + sm;
                #pragma unroll
                for (int dt = 0; dt < 2; ++dt)
                    #pragma unroll
                    for (int e = 0; e < 16; ++e) o_acc[dt][e] *= al;

                // P: C-layout -> B-layout via cross-half register exchange.
                // groups of 4 rows; partner half holds the complementary rows.
                bf16x8 pf[4];
                {
                    uint32_t d0 = pkbf(s0[0],  s0[1]),  d1 = pkbf(s0[2],  s0[3]);
                    uint32_t d2 = pkbf(s0[4],  s0[5]),  d3 = pkbf(s0[6],  s0[7]);
                    uint32_t d4 = pkbf(s0[8],  s0[9]),  d5 = pkbf(s0[10], s0[11]);
                    uint32_t d6 = pkbf(s0[12], s0[13]), d7 = pkbf(s0[14], s0[15]);
                    uint32_t x0 = __shfl_xor((int)d0, 32), x1 = __shfl_xor((int)d1, 32);
                    uint32_t x2 = __shfl_xor((int)d2, 32), x3 = __shfl_xor((int)d3, 32);
                    uint32_t x4 = __shfl_xor((int)d4, 32), x5 = __shfl_xor((int)d5, 32);
                    uint32_t x6 = __shfl_xor((int)d6, 32), x7 = __shfl_xor((int)d7, 32);
                    pf[0] = half ? mk8(x2, x3, d2, d3) : mk8(d0, d1, x0, x1);
                    pf[1] = half ? mk8(x6, x7, d6, d7) : mk8(d4, d5, x4, x5);
                }
                if (act1) {
                    uint32_t d0 = pkbf(s1[0],  s1[1]),  d1 = pkbf(s1[2],  s1[3]);
                    uint32_t d2 = pkbf(s1[4],  s1[5]),  d3 = pkbf(s1[6],  s1[7]);
                    uint32_t d4 = pkbf(s1[8],  s1[9]),  d5 = pkbf(s1[10], s1[11]);
                    uint32_t d6 = pkbf(s1[12], s1[13]), d7 = pkbf(s1[14], s1[15]);
                    uint32_t x0 = __shfl_xor((int)d0, 32), x1 = __shfl_xor((int)d1, 32);
                    uint32_t x2 = __shfl_xor((int)d2, 32), x3 = __shfl_xor((int)d3, 32);
                    uint32_t x4 = __shfl_xor((int)d4, 32), x5 = __shfl_xor((int)d5, 32);
                    uint32_t x6 = __shfl_xor((int)d6, 32), x7 = __shfl_xor((int)d7, 32);
                    pf[2] = half ? mk8(x2, x3, d2, d3) : mk8(d0, d1, x0, x1);
                    pf[3] = half ? mk8(x6, x7, d6, d7) : mk8(d4, d5, x4, x5);
                }

                // O^T += V^T * P^T over kpos chunks
                const int nc = act1 ? 4 : 2;
                #pragma unroll
                for (int c = 0; c < 4; ++c) {
                    if (c >= nc) break;
                    #pragma unroll
                    for (int dt = 0; dt < 2; ++dt)
                        o_acc[dt] = __builtin_amdgcn_mfma_f32_32x32x16_bf16(
                            vf[dt][c], pf[c], o_acc[dt], 0, 0, 0);
                }
            }
            __syncthreads();
        }

        // epilogue: O^T C-layout -> Ob (b, s, h*64+d); q = l32 same-lane
        const float inv = 1.f / l_i;
        bf16* op = O + ((size_t)(b * S_ + qa) * H_ + h) * DH_;
        #pragma unroll
        for (int dt = 0; dt < 2; ++dt)
            #pragma unroll
            for (int g = 0; g < 4; ++g) {
                bf16x4 ov;
                #pragma unroll
                for (int r = 0; r < 4; ++r) ov[r] = (bf16)(o_acc[dt][g * 4 + r] * inv);
                *(bf16x4*)(op + dt * 32 + g * 8 + half * 4) = ov;
            }
        __syncthreads();   // LDS reuse safety before next phase's prefetch
    }
}

// ---------------------------------------------------------------------------
extern "C" void kernel_launch(void* const* d_in, const int* in_sizes, int n_in,
                              void* d_out, int out_size, void* d_ws, size_t ws_size,
                              hipStream_t stream)
{
    const float* X    = (const float*)d_in[0];
    const float* cs   = (const float*)d_in[1];
    const float* sn   = (const float*)d_in[2];
    const float* Wq   = (const float*)d_in[4];
    const float* Wk   = (const float*)d_in[5];
    const float* Wv   = (const float*)d_in[6];
    const float* Wo   = (const float*)d_in[7];
    float* Y          = (float*)d_out;

    bf16* Xb  = (bf16*)d_ws;                       // 8388608
    bf16* Wqb = Xb  + (size_t)8388608;             // 4194304
    bf16* Wkb = Wqb + (size_t)4194304;             // 1048576
    bf16* Wvb = Wkb + (size_t)1048576;             // 1048576
    bf16* Wob = Wvb + (size_t)1048576;             // 4194304
    bf16* Qb  = Wob + (size_t)4194304;             // 8388608
    bf16* Kb  = Qb  + (size_t)8388608;             // 2097152
    bf16* Vtb = Kb  + (size_t)2097152;             // 2097152 (transposed d,s)
    bf16* Ob  = Vtb + (size_t)2097152;             // 8388608

    dim3 blk(256);
    cvt_all_kernel<<<dim3(9216), blk, 0, stream>>>(X, Wq, Wk, Wv, Wo,
                                                   Xb, Wqb, Wkb, Wvb, Wob);
    gemm_qkv_kernel<<<dim3(32, 24), blk, 0, stream>>>(Xb, Wqb, Wkb, Wvb,
                                                      cs, sn, Qb, Kb, Vtb);
    attn_kernel<<<dim3(8, H_, B_), blk, 0, stream>>>(Qb, Kb, Vtb, Ob);
    gemm_out_kernel<<<dim3(32, 16), blk, 0, stream>>>(Ob, Wob, Y);
}